// Round 1
// baseline (2026.590 us; speedup 1.0000x reference)
//
#include <hip/hip_runtime.h>
#include <hip/hip_bf16.h>

#define NODES 50000
#define E0    800000
#define ETOT  (E0 + NODES)   // 850000 edges incl. self-loops

// ======================= GEMM: C = act(A @ B + bias) =======================
// A [M,K] f32 row-major, B [K,N] f32 row-major. 64x64 tile, BK=16,
// 256 threads, 4x4 microtile. LDS stride 68 -> float4-aligned, <=2-way banks.
__global__ __launch_bounds__(256) void gemm_bias_act(
    const float* __restrict__ A, const float* __restrict__ B,
    const float* __restrict__ bias, float* __restrict__ C,
    int M, int N, int K, int relu)
{
    __shared__ float As[16][68];   // [k][m]
    __shared__ float Bs[16][68];   // [k][n]
    const int tid = threadIdx.x;
    const int bm = blockIdx.y * 64, bn = blockIdx.x * 64;
    const int tx = tid & 15, ty = tid >> 4;
    float acc[4][4] = {};

    for (int k0 = 0; k0 < K; k0 += 16) {
        {   // A tile 64x16 -> As transposed
            int r = tid >> 2, c4 = (tid & 3) * 4;
            int row = bm + r; if (row >= M) row = M - 1;
            const float4 v = *(const float4*)(&A[(size_t)row * K + k0 + c4]);
            As[c4+0][r] = v.x; As[c4+1][r] = v.y; As[c4+2][r] = v.z; As[c4+3][r] = v.w;
        }
        {   // B tile 16x64
            int r = tid >> 4, c4 = (tid & 15) * 4;
            *(float4*)(&Bs[r][c4]) = *(const float4*)(&B[(size_t)(k0 + r) * N + bn + c4]);
        }
        __syncthreads();
        #pragma unroll
        for (int k = 0; k < 16; k++) {
            float4 a = *(const float4*)(&As[k][ty*4]);
            float4 b = *(const float4*)(&Bs[k][tx*4]);
            float av[4] = {a.x,a.y,a.z,a.w};
            float bv[4] = {b.x,b.y,b.z,b.w};
            #pragma unroll
            for (int i = 0; i < 4; i++)
                #pragma unroll
                for (int j = 0; j < 4; j++) acc[i][j] += av[i]*bv[j];
        }
        __syncthreads();
    }
    #pragma unroll
    for (int i = 0; i < 4; i++) {
        int row = bm + ty*4 + i;
        if (row >= M) continue;
        float4 o;
        float* op = &o.x;
        #pragma unroll
        for (int j = 0; j < 4; j++) {
            int col = bn + tx*4 + j;
            float v = acc[i][j] + (bias ? bias[col] : 0.f);
            if (relu) v = fmaxf(v, 0.f);
            op[j] = v;
        }
        *(float4*)(&C[(size_t)row * N + bn + tx*4]) = o;
    }
}

// Small GEMM for N=8 (wc3): one thread per (m,n).
__global__ void gemm_n8(const float* __restrict__ A, const float* __restrict__ B,
                        float* __restrict__ C, int M, int K)
{
    int t = blockIdx.x * 256 + threadIdx.x;
    int m = t >> 3, n = t & 7;
    if (m >= M) return;
    float s = 0.f;
    const float4* A4 = (const float4*)(A + (size_t)m * K);
    for (int k4 = 0; k4 < K/4; k4++) {
        float4 a = A4[k4];
        s += a.x * B[(k4*4+0)*8+n] + a.y * B[(k4*4+1)*8+n]
           + a.z * B[(k4*4+2)*8+n] + a.w * B[(k4*4+3)*8+n];
    }
    C[t] = s;
}

// ======================= GAT attention =======================
// one 64-lane wave per (node,head): a_src/a_dst dot products. gw = n*H+h.
__global__ void attn_scores(const float* __restrict__ hc, const float* __restrict__ att_s,
                            const float* __restrict__ att_d, float* __restrict__ aS,
                            float* __restrict__ aD, int nwaves, int hmask, int C)
{
    int gw = (blockIdx.x * blockDim.x + threadIdx.x) >> 6;
    int lane = threadIdx.x & 63;
    if (gw >= nwaves) return;
    int h = gw & hmask;
    float vs = 0.f, vd = 0.f;
    if (lane < C) {
        float xv = hc[(size_t)gw * C + lane];
        vs = xv * att_s[h*C + lane];
        vd = xv * att_d[h*C + lane];
    }
    #pragma unroll
    for (int off = 32; off; off >>= 1) {
        vs += __shfl_xor(vs, off);
        vd += __shfl_xor(vd, off);
    }
    if (lane == 0) { aS[gw] = vs; aD[gw] = vd; }
}

__device__ __forceinline__ unsigned encf(float f) {
    unsigned u = __float_as_uint(f);
    return (u & 0x80000000u) ? ~u : (u | 0x80000000u);
}

__device__ __forceinline__ void edge_sd(int e, int& s, int& d,
                                        const int* __restrict__ src,
                                        const int* __restrict__ dst) {
    if (e < E0) { s = src[e]; d = dst[e]; } else { s = e - E0; d = s; }
}

__global__ void edge_max(const int* __restrict__ src, const int* __restrict__ dst,
                         const float* __restrict__ aS, const float* __restrict__ aD,
                         unsigned* __restrict__ menc, int hp, int hmask)
{
    int t = blockIdx.x * blockDim.x + threadIdx.x;
    if (t >= (ETOT << hp)) return;
    int e = t >> hp, h = t & hmask;
    int s, d; edge_sd(e, s, d, src, dst);
    float v = aS[(s << hp) + h] + aD[(d << hp) + h];
    v = v > 0.f ? v : 0.2f * v;
    atomicMax(&menc[(d << hp) + h], encf(v));
}

__global__ void decode_max(unsigned* __restrict__ m, int n)
{
    int i = blockIdx.x * blockDim.x + threadIdx.x;
    if (i >= n) return;
    unsigned u = m[i];
    unsigned b = (u & 0x80000000u) ? (u ^ 0x80000000u) : ~u;
    float f = __uint_as_float(b);
    if (!isfinite(f)) f = 0.f;
    ((float*)m)[i] = f;
}

__global__ void edge_expsum(const int* __restrict__ src, const int* __restrict__ dst,
                            const float* __restrict__ aS, const float* __restrict__ aD,
                            const float* __restrict__ m, float* __restrict__ denom,
                            float* __restrict__ alpha, int hp, int hmask)
{
    int t = blockIdx.x * blockDim.x + threadIdx.x;
    if (t >= (ETOT << hp)) return;
    int e = t >> hp, h = t & hmask;
    int s, d; edge_sd(e, s, d, src, dst);
    float v = aS[(s << hp) + h] + aD[(d << hp) + h];
    v = v > 0.f ? v : 0.2f * v;
    float ex = expf(v - m[(d << hp) + h]);
    alpha[t] = ex;
    atomicAdd(&denom[(d << hp) + h], ex);
}

__global__ void alpha_div(const int* __restrict__ src, const int* __restrict__ dst,
                          const float* __restrict__ denom, float* __restrict__ alpha,
                          int hp, int hmask)
{
    int t = blockIdx.x * blockDim.x + threadIdx.x;
    if (t >= (ETOT << hp)) return;
    int e = t >> hp, h = t & hmask;
    int s, d; edge_sd(e, s, d, src, dst);
    alpha[t] = alpha[t] / fmaxf(denom[(d << hp) + h], 1e-16f);
}

// scatter: one thread per (edge, channel); out[dst] += alpha * h[src]
__global__ void edge_scatter(const int* __restrict__ src, const int* __restrict__ dst,
                             const float* __restrict__ alpha, const float* __restrict__ h,
                             float* __restrict__ out, int hp, int cshift, int hcshift)
{
    long long t = (long long)blockIdx.x * blockDim.x + threadIdx.x;
    if (t >= ((long long)ETOT << hcshift)) return;
    int e = (int)(t >> hcshift);
    int c = (int)(t & ((1 << hcshift) - 1));
    int hh = c >> cshift;
    int s, d; edge_sd(e, s, d, src, dst);
    float a = alpha[(e << hp) + hh];
    atomicAdd(&out[(d << hcshift) + c], a * h[(s << hcshift) + c]);
}

__global__ void bias_act(float* __restrict__ x, const float* __restrict__ bias,
                         int total, int cmask, int elu)
{
    int i = blockIdx.x * blockDim.x + threadIdx.x;
    if (i >= total) return;
    float v = x[i] + bias[i & cmask];
    if (elu) v = v > 0.f ? v : expm1f(v);
    x[i] = v;
}

// ======================= launch =======================
extern "C" void kernel_launch(void* const* d_in, const int* in_sizes, int n_in,
                              void* d_out, int out_size, void* d_ws, size_t ws_size,
                              hipStream_t stream)
{
    const float* x   = (const float*)d_in[0];
    const int*   ei  = (const int*)d_in[1];
    const float* w1  = (const float*)d_in[2];  const float* b1  = (const float*)d_in[3];
    const float* w2  = (const float*)d_in[4];  const float* b2  = (const float*)d_in[5];
    const float* w3  = (const float*)d_in[6];  const float* b3  = (const float*)d_in[7];
    const float* wc1 = (const float*)d_in[8];  const float* as1 = (const float*)d_in[9];
    const float* ad1 = (const float*)d_in[10]; const float* bc1 = (const float*)d_in[11];
    const float* wc2 = (const float*)d_in[12]; const float* as2 = (const float*)d_in[13];
    const float* ad2 = (const float*)d_in[14]; const float* bc2 = (const float*)d_in[15];
    const float* wc3 = (const float*)d_in[16]; const float* as3 = (const float*)d_in[17];
    const float* ad3 = (const float*)d_in[18]; const float* bc3 = (const float*)d_in[19];

    const int* srcv = ei;        // [E0]
    const int* dstv = ei + E0;   // [E0]

    // -------- workspace layout (bytes) --------
    // A region (102.4MB): h1; later hc1(51.2M)+out2(25.6M)+hc3(1.6M)
    // B region (51.2MB) : h2; later out1
    // C region (25.6MB) : h3; later hc2
    // D region          : aS, aD, menc/m, denom, alpha
    char* ws = (char*)d_ws;
    float*    h1    = (float*)(ws + 0);
    float*    hc1   = (float*)(ws + 0);
    float*    out2  = (float*)(ws + 51200000);
    float*    hc3   = (float*)(ws + 76800000);
    float*    h2    = (float*)(ws + 102400000);
    float*    out1  = (float*)(ws + 102400000);
    float*    h3    = (float*)(ws + 153600000);
    float*    hc2   = (float*)(ws + 153600000);
    float*    aS    = (float*)(ws + 179200000);
    float*    aD    = (float*)(ws + 180000000);
    unsigned* menc  = (unsigned*)(ws + 180800000);
    float*    mflt  = (float*)(ws + 180800000);
    float*    denom = (float*)(ws + 181600000);
    float*    alpha = (float*)(ws + 182400000);   // ETOT*4 floats = 13.6MB
    if (ws_size < (size_t)196000000) return;      // need ~196MB scratch

    float* outf = (float*)d_out;
    dim3 blk(256);
    const int gy = (NODES + 63) / 64;

    // -------- MLP --------
    gemm_bias_act<<<dim3(8, gy), blk, 0, stream>>>(x,  w1, b1, h1, NODES, 512, 256, 1);
    gemm_bias_act<<<dim3(4, gy), blk, 0, stream>>>(h1, w2, b2, h2, NODES, 256, 512, 1);
    gemm_bias_act<<<dim3(2, gy), blk, 0, stream>>>(h2, w3, b3, h3, NODES, 128, 256, 1);

    // -------- GAT layer helper macro --------
    #define GAT_ATTN(HIN, HP, HMASK, C, CSHIFT, HCSHIFT, OUTBUF)                               \
    {                                                                                          \
        const int NH = NODES << HP;                                                            \
        attn_scores<<<(NH*64 + 255)/256, blk, 0, stream>>>(HIN, lay_as, lay_ad, aS, aD,        \
                                                           NH, HMASK, C);                      \
        (void)hipMemsetAsync(menc, 0, (size_t)NH*4, stream);                                   \
        edge_max<<<((ETOT<<HP) + 255)/256, blk, 0, stream>>>(srcv, dstv, aS, aD, menc,         \
                                                             HP, HMASK);                       \
        decode_max<<<(NH + 255)/256, blk, 0, stream>>>(menc, NH);                              \
        (void)hipMemsetAsync(denom, 0, (size_t)NH*4, stream);                                  \
        edge_expsum<<<((ETOT<<HP) + 255)/256, blk, 0, stream>>>(srcv, dstv, aS, aD, mflt,      \
                                                                denom, alpha, HP, HMASK);      \
        alpha_div<<<((ETOT<<HP) + 255)/256, blk, 0, stream>>>(srcv, dstv, denom, alpha,        \
                                                              HP, HMASK);                      \
        edge_scatter<<<(int)((((long long)ETOT<<HCSHIFT) + 255)/256), blk, 0, stream>>>(       \
            srcv, dstv, alpha, HIN, OUTBUF, HP, CSHIFT, HCSHIFT);                              \
    }

    // -------- GAT1: H=4, C=64, concat -> 256 --------
    gemm_bias_act<<<dim3(4, gy), blk, 0, stream>>>(h3, wc1, nullptr, hc1, NODES, 256, 128, 0);
    {
        const float* lay_as = as1; const float* lay_ad = ad1;
        (void)hipMemsetAsync(out1, 0, (size_t)NODES*256*4, stream);
        GAT_ATTN(hc1, 2, 3, 64, 6, 8, out1);
        bias_act<<<(NODES*256 + 255)/256, blk, 0, stream>>>(out1, bc1, NODES*256, 255, 1);
    }

    // -------- GAT2: H=4, C=32, concat -> 128 --------
    gemm_bias_act<<<dim3(2, gy), blk, 0, stream>>>(out1, wc2, nullptr, hc2, NODES, 128, 256, 0);
    {
        const float* lay_as = as2; const float* lay_ad = ad2;
        (void)hipMemsetAsync(out2, 0, (size_t)NODES*128*4, stream);
        GAT_ATTN(hc2, 2, 3, 32, 5, 7, out2);
        bias_act<<<(NODES*128 + 255)/256, blk, 0, stream>>>(out2, bc2, NODES*128, 127, 1);
    }

    // -------- GAT3: H=1, C=8, mean(=identity) -> 8, no ELU --------
    gemm_n8<<<(NODES*8 + 255)/256, blk, 0, stream>>>(out2, wc3, hc3, NODES, 128);
    {
        const float* lay_as = as3; const float* lay_ad = ad3;
        (void)hipMemsetAsync(outf, 0, (size_t)NODES*8*4, stream);
        GAT_ATTN(hc3, 0, 0, 8, 3, 3, outf);
        bias_act<<<(NODES*8 + 255)/256, blk, 0, stream>>>(outf, bc3, NODES*8, 7, 0);
    }
    #undef GAT_ATTN
}

// Round 2
// 1187.996 us; speedup vs baseline: 1.7059x; 1.7059x over previous
//
#include <hip/hip_runtime.h>
#include <hip/hip_bf16.h>

#define NODES 50000
#define E0    800000
#define ETOT  (E0 + NODES)   // 850000 edges incl. self-loops

// ======================= GEMM: C = act(A @ B + bias) =======================
// A [M,K] f32 row-major, B [K,N] f32 row-major. 64x64 tile, BK=16,
// 256 threads, 4x4 microtile. LDS stride 68 -> float4-aligned, <=2-way banks.
__global__ __launch_bounds__(256) void gemm_bias_act(
    const float* __restrict__ A, const float* __restrict__ B,
    const float* __restrict__ bias, float* __restrict__ C,
    int M, int N, int K, int relu)
{
    __shared__ float As[16][68];   // [k][m]
    __shared__ float Bs[16][68];   // [k][n]
    const int tid = threadIdx.x;
    const int bm = blockIdx.y * 64, bn = blockIdx.x * 64;
    const int tx = tid & 15, ty = tid >> 4;
    float acc[4][4] = {};

    for (int k0 = 0; k0 < K; k0 += 16) {
        {   // A tile 64x16 -> As transposed
            int r = tid >> 2, c4 = (tid & 3) * 4;
            int row = bm + r; if (row >= M) row = M - 1;
            const float4 v = *(const float4*)(&A[(size_t)row * K + k0 + c4]);
            As[c4+0][r] = v.x; As[c4+1][r] = v.y; As[c4+2][r] = v.z; As[c4+3][r] = v.w;
        }
        {   // B tile 16x64
            int r = tid >> 4, c4 = (tid & 15) * 4;
            *(float4*)(&Bs[r][c4]) = *(const float4*)(&B[(size_t)(k0 + r) * N + bn + c4]);
        }
        __syncthreads();
        #pragma unroll
        for (int k = 0; k < 16; k++) {
            float4 a = *(const float4*)(&As[k][ty*4]);
            float4 b = *(const float4*)(&Bs[k][tx*4]);
            float av[4] = {a.x,a.y,a.z,a.w};
            float bv[4] = {b.x,b.y,b.z,b.w};
            #pragma unroll
            for (int i = 0; i < 4; i++)
                #pragma unroll
                for (int j = 0; j < 4; j++) acc[i][j] += av[i]*bv[j];
        }
        __syncthreads();
    }
    #pragma unroll
    for (int i = 0; i < 4; i++) {
        int row = bm + ty*4 + i;
        if (row >= M) continue;
        float4 o;
        float* op = &o.x;
        #pragma unroll
        for (int j = 0; j < 4; j++) {
            int col = bn + tx*4 + j;
            float v = acc[i][j] + (bias ? bias[col] : 0.f);
            if (relu) v = fmaxf(v, 0.f);
            op[j] = v;
        }
        *(float4*)(&C[(size_t)row * N + bn + tx*4]) = o;
    }
}

// Small GEMM for N=8 (wc3): one thread per (m,n).
__global__ void gemm_n8(const float* __restrict__ A, const float* __restrict__ B,
                        float* __restrict__ C, int M, int K)
{
    int t = blockIdx.x * 256 + threadIdx.x;
    int m = t >> 3, n = t & 7;
    if (m >= M) return;
    float s = 0.f;
    const float4* A4 = (const float4*)(A + (size_t)m * K);
    for (int k4 = 0; k4 < K/4; k4++) {
        float4 a = A4[k4];
        s += a.x * B[(k4*4+0)*8+n] + a.y * B[(k4*4+1)*8+n]
           + a.z * B[(k4*4+2)*8+n] + a.w * B[(k4*4+3)*8+n];
    }
    C[t] = s;
}

// ======================= attention scores =======================
// one 64-lane wave per (node,head): a_src/a_dst dot products. gw = n*H+h.
__global__ void attn_scores(const float* __restrict__ hc, const float* __restrict__ att_s,
                            const float* __restrict__ att_d, float* __restrict__ aS,
                            float* __restrict__ aD, int nwaves, int hmask, int C)
{
    int gw = (blockIdx.x * blockDim.x + threadIdx.x) >> 6;
    int lane = threadIdx.x & 63;
    if (gw >= nwaves) return;
    int h = gw & hmask;
    float vs = 0.f, vd = 0.f;
    if (lane < C) {
        float xv = hc[(size_t)gw * C + lane];
        vs = xv * att_s[h*C + lane];
        vd = xv * att_d[h*C + lane];
    }
    #pragma unroll
    for (int off = 32; off; off >>= 1) {
        vs += __shfl_xor(vs, off);
        vd += __shfl_xor(vd, off);
    }
    if (lane == 0) { aS[gw] = vs; aD[gw] = vd; }
}

// ======================= CSR build (by dst) =======================
__device__ __forceinline__ void edge_sd(int e, int& s, int& d,
                                        const int* __restrict__ src,
                                        const int* __restrict__ dst) {
    if (e < E0) { s = src[e]; d = dst[e]; } else { s = e - E0; d = s; }
}

__global__ void deg_hist(const int* __restrict__ src, const int* __restrict__ dst,
                         int* __restrict__ deg)
{
    int e = blockIdx.x * 256 + threadIdx.x;
    if (e >= ETOT) return;
    int s, d; edge_sd(e, s, d, src, dst);
    atomicAdd(&deg[d], 1);
}

// exclusive scan, 256 elements per block -> partial in ptr, block total in bsum
__global__ void scan_block(const int* __restrict__ deg, int* __restrict__ ptr,
                           int* __restrict__ bsum, int n)
{
    __shared__ int sm[256];
    int t = threadIdx.x, i = blockIdx.x * 256 + t;
    int v = (i < n) ? deg[i] : 0;
    sm[t] = v; __syncthreads();
    #pragma unroll
    for (int off = 1; off < 256; off <<= 1) {
        int x = (t >= off) ? sm[t - off] : 0;
        __syncthreads();
        sm[t] += x; __syncthreads();
    }
    if (i < n) ptr[i] = sm[t] - v;          // exclusive
    if (t == 255) bsum[blockIdx.x] = sm[255];
}

__global__ void scan_bsum(int* __restrict__ bsum, int nb)
{
    __shared__ int sm[256];
    int t = threadIdx.x;
    int v = (t < nb) ? bsum[t] : 0;
    sm[t] = v; __syncthreads();
    #pragma unroll
    for (int off = 1; off < 256; off <<= 1) {
        int x = (t >= off) ? sm[t - off] : 0;
        __syncthreads();
        sm[t] += x; __syncthreads();
    }
    if (t < nb) bsum[t] = sm[t] - v;        // exclusive
}

__global__ void scan_add(int* __restrict__ ptr, const int* __restrict__ bsum, int n)
{
    int i = blockIdx.x * 256 + threadIdx.x;
    if (i < n) ptr[i] += bsum[blockIdx.x];
    if (i == 0) ptr[n] = ETOT;
}

__global__ void csr_fill(const int* __restrict__ src, const int* __restrict__ dst,
                         const int* __restrict__ ptr, int* __restrict__ cursor,
                         int* __restrict__ csr)
{
    int e = blockIdx.x * 256 + threadIdx.x;
    if (e >= ETOT) return;
    int s, d; edge_sd(e, s, d, src, dst);
    int pos = ptr[d] + atomicAdd(&cursor[d], 1);
    csr[pos] = s;
}

// ======================= fused GAT layer =======================
// One dst-slot of W=H*C threads per node. Lane-parallel online softmax over
// incoming edges (shuffle-combined within each C-group), then serial
// accumulation pass gathering h[src] rows (coalesced across the slot).
template<int H, int C>
__global__ __launch_bounds__(256) void gat_fused(
    const float* __restrict__ hf, const float* __restrict__ aS,
    const float* __restrict__ aDv, const int* __restrict__ ptr,
    const int* __restrict__ csr, const float* __restrict__ bias,
    float* __restrict__ out, int elu)
{
    constexpr int W = H * C;
    const int tl = threadIdx.x % W;
    const int dsub = threadIdx.x / W;
    const int d = blockIdx.x * (256 / W) + dsub;
    if (d >= NODES) return;
    const int h = tl / C, c = tl % C;
    const int beg = ptr[d], end = ptr[d + 1];
    const float aDd = aDv[d * H + h];

    // online softmax (m, den) per lane, edges strided by C within the group
    float m = -1e30f, den = 0.f;
    for (int i = beg + c; i < end; i += C) {
        int s = csr[i];
        float e = aS[s * H + h] + aDd;
        e = e > 0.f ? e : 0.2f * e;
        float M = fmaxf(m, e);
        den = den * __expf(m - M) + __expf(e - M);
        m = M;
    }
    #pragma unroll
    for (int off = C >> 1; off; off >>= 1) {
        float mo = __shfl_xor(m, off);
        float dn = __shfl_xor(den, off);
        float M = fmaxf(m, mo);
        den = den * __expf(m - M) + dn * __expf(mo - M);
        m = M;
    }

    // weighted aggregation: acc = sum_e exp(e_e - m) * h[src_e][h*C+c]
    float acc = 0.f;
    for (int i = beg; i < end; i++) {
        int s = csr[i];
        float e = aS[s * H + h] + aDd;
        e = e > 0.f ? e : 0.2f * e;
        float w = __expf(e - m);
        acc += w * hf[(size_t)s * W + tl];
    }
    float v = acc / den + bias[tl];
    if (elu) v = v > 0.f ? v : expm1f(v);
    out[(size_t)d * W + tl] = v;
}

// ======================= launch =======================
extern "C" void kernel_launch(void* const* d_in, const int* in_sizes, int n_in,
                              void* d_out, int out_size, void* d_ws, size_t ws_size,
                              hipStream_t stream)
{
    const float* x   = (const float*)d_in[0];
    const int*   ei  = (const int*)d_in[1];
    const float* w1  = (const float*)d_in[2];  const float* b1  = (const float*)d_in[3];
    const float* w2  = (const float*)d_in[4];  const float* b2  = (const float*)d_in[5];
    const float* w3  = (const float*)d_in[6];  const float* b3  = (const float*)d_in[7];
    const float* wc1 = (const float*)d_in[8];  const float* as1 = (const float*)d_in[9];
    const float* ad1 = (const float*)d_in[10]; const float* bc1 = (const float*)d_in[11];
    const float* wc2 = (const float*)d_in[12]; const float* as2 = (const float*)d_in[13];
    const float* ad2 = (const float*)d_in[14]; const float* bc2 = (const float*)d_in[15];
    const float* wc3 = (const float*)d_in[16]; const float* as3 = (const float*)d_in[17];
    const float* ad3 = (const float*)d_in[18]; const float* bc3 = (const float*)d_in[19];

    const int* srcv = ei;        // [E0]
    const int* dstv = ei + E0;   // [E0]

    // -------- workspace layout (bytes) --------
    char* ws = (char*)d_ws;
    float*    h1    = (float*)(ws + 0);            // 102.4 MB
    float*    hc1   = (float*)(ws + 0);            //  51.2 MB (after h1 dead)
    float*    out2  = (float*)(ws + 51200000);     //  25.6 MB
    float*    hc3   = (float*)(ws + 76800000);     //   1.6 MB
    float*    h2    = (float*)(ws + 102400000);    //  51.2 MB
    float*    out1  = (float*)(ws + 102400000);    //  51.2 MB (after h2 dead)
    float*    h3    = (float*)(ws + 153600000);    //  25.6 MB
    float*    hc2   = (float*)(ws + 153600000);    //  25.6 MB (after h3 dead)
    float*    aS    = (float*)(ws + 179200000);    //   0.8 MB
    float*    aD    = (float*)(ws + 180000000);    //   0.8 MB
    int*      ptr   = (int*)  (ws + 182400000);    //  50001 ints
    int*      deg   = (int*)  (ws + 182700000);    //  50000 ints (also cursor)
    int*      bsum  = (int*)  (ws + 182950000);    //  256 ints
    int*      csr   = (int*)  (ws + 183000000);    //  850000 ints (3.4 MB)
    if (ws_size < (size_t)196000000) return;

    float* outf = (float*)d_out;
    dim3 blk(256);
    const int gy = (NODES + 63) / 64;
    const int NB_SCAN = (NODES + 255) / 256;       // 196

    // -------- CSR build (graph shared by all 3 GAT layers) --------
    (void)hipMemsetAsync(deg, 0, (size_t)NODES * 4, stream);
    deg_hist<<<(ETOT + 255)/256, blk, 0, stream>>>(srcv, dstv, deg);
    scan_block<<<NB_SCAN, blk, 0, stream>>>(deg, ptr, bsum, NODES);
    scan_bsum<<<1, blk, 0, stream>>>(bsum, NB_SCAN);
    scan_add<<<NB_SCAN, blk, 0, stream>>>(ptr, bsum, NODES);
    (void)hipMemsetAsync(deg, 0, (size_t)NODES * 4, stream);   // reuse as cursor
    csr_fill<<<(ETOT + 255)/256, blk, 0, stream>>>(srcv, dstv, ptr, deg, csr);

    // -------- MLP --------
    gemm_bias_act<<<dim3(8, gy), blk, 0, stream>>>(x,  w1, b1, h1, NODES, 512, 256, 1);
    gemm_bias_act<<<dim3(4, gy), blk, 0, stream>>>(h1, w2, b2, h2, NODES, 256, 512, 1);
    gemm_bias_act<<<dim3(2, gy), blk, 0, stream>>>(h2, w3, b3, h3, NODES, 128, 256, 1);

    // -------- GAT1: H=4, C=64, concat -> 256, ELU --------
    gemm_bias_act<<<dim3(4, gy), blk, 0, stream>>>(h3, wc1, nullptr, hc1, NODES, 256, 128, 0);
    attn_scores<<<(NODES*4*64 + 255)/256, blk, 0, stream>>>(hc1, as1, ad1, aS, aD,
                                                            NODES*4, 3, 64);
    gat_fused<4,64><<<NODES, blk, 0, stream>>>(hc1, aS, aD, ptr, csr, bc1, out1, 1);

    // -------- GAT2: H=4, C=32, concat -> 128, ELU --------
    gemm_bias_act<<<dim3(2, gy), blk, 0, stream>>>(out1, wc2, nullptr, hc2, NODES, 128, 256, 0);
    attn_scores<<<(NODES*4*64 + 255)/256, blk, 0, stream>>>(hc2, as2, ad2, aS, aD,
                                                            NODES*4, 3, 32);
    gat_fused<4,32><<<(NODES+1)/2, blk, 0, stream>>>(hc2, aS, aD, ptr, csr, bc2, out2, 1);

    // -------- GAT3: H=1, C=8, mean(=identity) -> 8, no ELU --------
    gemm_n8<<<(NODES*8 + 255)/256, blk, 0, stream>>>(out2, wc3, hc3, NODES, 128);
    attn_scores<<<(NODES*64 + 255)/256, blk, 0, stream>>>(hc3, as3, ad3, aS, aD,
                                                          NODES, 0, 8);
    gat_fused<1,8><<<(NODES + 31)/32, blk, 0, stream>>>(hc3, aS, aD, ptr, csr, bc3, outf, 0);
}

// Round 3
// 1013.351 us; speedup vs baseline: 1.9999x; 1.1723x over previous
//
#include <hip/hip_runtime.h>
#include <hip/hip_bf16.h>

#define NODES 50000
#define E0    800000
#define ETOT  (E0 + NODES)   // 850000 edges incl. self-loops

typedef short  short8 __attribute__((ext_vector_type(8)));
typedef float  f32x4  __attribute__((ext_vector_type(4)));
typedef __hip_bfloat16 bf16;

__device__ __forceinline__ float ldf(const float* p) { return *p; }
__device__ __forceinline__ float ldf(const bf16* p)  { return __bfloat162float(*p); }
__device__ __forceinline__ void  stf(float* p, float v) { *p = v; }
__device__ __forceinline__ void  stf(bf16* p, float v)  { *p = __float2bfloat16(v); }

// ======================= conversions =======================
__global__ void f32_to_bf16(const float* __restrict__ in, bf16* __restrict__ out, int n4)
{
    int i = blockIdx.x * 256 + threadIdx.x;
    if (i >= n4) return;
    float4 v = *(const float4*)(in + (size_t)i * 4);
    bf16* o = out + (size_t)i * 4;
    o[0] = __float2bfloat16(v.x); o[1] = __float2bfloat16(v.y);
    o[2] = __float2bfloat16(v.z); o[3] = __float2bfloat16(v.w);
}

// w [K][N] f32 -> wT [N][K] bf16
__global__ void w_transpose_bf16(const float* __restrict__ w, bf16* __restrict__ wt,
                                 int K, int N)
{
    int t = blockIdx.x * 256 + threadIdx.x;
    if (t >= K * N) return;
    int k = t / N, n = t % N;
    wt[(size_t)n * K + k] = __float2bfloat16(w[t]);
}

// ======================= bf16 MFMA GEMM =======================
// A [M,K] bf16 row-major, Bt [N,K] bf16 (B transposed), C [M,N] bf16.
// 128x128 tile, BK=32, 4 waves, each wave 64x64 via 4x4 mfma_f32_16x16x32_bf16.
__global__ __launch_bounds__(256) void mfma_gemm(
    const bf16* __restrict__ A, const bf16* __restrict__ Bt,
    const float* __restrict__ bias, bf16* __restrict__ C,
    int M, int N, int K, int relu)
{
    __shared__ alignas(16) unsigned short Abuf[128 * 32];
    __shared__ alignas(16) unsigned short Bbuf[128 * 32];
    const int tid  = threadIdx.x;
    const int wave = tid >> 6, lane = tid & 63;
    const int bm = blockIdx.y * 128, bn = blockIdx.x * 128;
    const int wr = (wave >> 1) * 64, wc = (wave & 1) * 64;
    const int lr = lane & 15, kg = lane >> 4;

    f32x4 acc[4][4];
    #pragma unroll
    for (int m = 0; m < 4; m++)
        #pragma unroll
        for (int n = 0; n < 4; n++)
            #pragma unroll
            for (int j = 0; j < 4; j++) acc[m][n][j] = 0.f;

    for (int k0 = 0; k0 < K; k0 += 32) {
        uint4 ra[2], rb[2];
        #pragma unroll
        for (int half = 0; half < 2; half++) {
            int t = tid + half * 256;
            int r = t >> 2, ko = (t & 3) * 8;
            int ar = bm + r; if (ar >= M) ar = M - 1;
            ra[half] = *(const uint4*)((const unsigned short*)A + (size_t)ar * K + k0 + ko);
            rb[half] = *(const uint4*)((const unsigned short*)Bt + (size_t)(bn + r) * K + k0 + ko);
        }
        __syncthreads();
        #pragma unroll
        for (int half = 0; half < 2; half++) {
            int t = tid + half * 256;
            *(uint4*)&Abuf[t * 8] = ra[half];
            *(uint4*)&Bbuf[t * 8] = rb[half];
        }
        __syncthreads();

        short8 af[4], bfr[4];
        #pragma unroll
        for (int m = 0; m < 4; m++)
            af[m] = *(const short8*)&Abuf[(wr + m * 16 + lr) * 32 + kg * 8];
        #pragma unroll
        for (int n = 0; n < 4; n++)
            bfr[n] = *(const short8*)&Bbuf[(wc + n * 16 + lr) * 32 + kg * 8];
        #pragma unroll
        for (int m = 0; m < 4; m++)
            #pragma unroll
            for (int n = 0; n < 4; n++)
                acc[m][n] = __builtin_amdgcn_mfma_f32_16x16x32_bf16(af[m], bfr[n], acc[m][n], 0, 0, 0);
    }

    // C/D layout: col = lane&15, row = (lane>>4)*4 + j   [m89-verified]
    #pragma unroll
    for (int m = 0; m < 4; m++) {
        int row0 = bm + wr + m * 16 + kg * 4;
        #pragma unroll
        for (int n = 0; n < 4; n++) {
            int col = bn + wc + n * 16 + lr;
            float bv = bias ? bias[col] : 0.f;
            #pragma unroll
            for (int j = 0; j < 4; j++) {
                int row = row0 + j;
                if (row < M) {
                    float v = acc[m][n][j] + bv;
                    if (relu) v = fmaxf(v, 0.f);
                    C[(size_t)row * N + col] = __float2bfloat16(v);
                }
            }
        }
    }
}

// Small GEMM for N=8 (wc3): one thread per (m,n). A bf16, B f32, C f32.
__global__ void gemm_n8(const bf16* __restrict__ A, const float* __restrict__ B,
                        float* __restrict__ C, int M, int K)
{
    int t = blockIdx.x * 256 + threadIdx.x;
    int m = t >> 3, n = t & 7;
    if (m >= M) return;
    float s = 0.f;
    #pragma unroll 4
    for (int k = 0; k < K; k++)
        s += __bfloat162float(A[(size_t)m * K + k]) * B[k * 8 + n];
    C[t] = s;
}

// ======================= attention scores =======================
template<typename T>
__global__ void attn_scores(const T* __restrict__ hc, const float* __restrict__ att_s,
                            const float* __restrict__ att_d, float* __restrict__ aS,
                            float* __restrict__ aD, int nwaves, int hmask, int C)
{
    int gw = (blockIdx.x * blockDim.x + threadIdx.x) >> 6;
    int lane = threadIdx.x & 63;
    if (gw >= nwaves) return;
    int h = gw & hmask;
    float vs = 0.f, vd = 0.f;
    if (lane < C) {
        float xv = ldf(&hc[(size_t)gw * C + lane]);
        vs = xv * att_s[h * C + lane];
        vd = xv * att_d[h * C + lane];
    }
    #pragma unroll
    for (int off = 32; off; off >>= 1) {
        vs += __shfl_xor(vs, off);
        vd += __shfl_xor(vd, off);
    }
    if (lane == 0) { aS[gw] = vs; aD[gw] = vd; }
}

// ======================= CSR build (by dst) =======================
__device__ __forceinline__ void edge_sd(int e, int& s, int& d,
                                        const int* __restrict__ src,
                                        const int* __restrict__ dst) {
    if (e < E0) { s = src[e]; d = dst[e]; } else { s = e - E0; d = s; }
}

__global__ void deg_hist(const int* __restrict__ src, const int* __restrict__ dst,
                         int* __restrict__ deg)
{
    int e = blockIdx.x * 256 + threadIdx.x;
    if (e >= ETOT) return;
    int s, d; edge_sd(e, s, d, src, dst);
    atomicAdd(&deg[d], 1);
}

__global__ void scan_block(const int* __restrict__ deg, int* __restrict__ ptr,
                           int* __restrict__ bsum, int n)
{
    __shared__ int sm[256];
    int t = threadIdx.x, i = blockIdx.x * 256 + t;
    int v = (i < n) ? deg[i] : 0;
    sm[t] = v; __syncthreads();
    #pragma unroll
    for (int off = 1; off < 256; off <<= 1) {
        int x = (t >= off) ? sm[t - off] : 0;
        __syncthreads();
        sm[t] += x; __syncthreads();
    }
    if (i < n) ptr[i] = sm[t] - v;
    if (t == 255) bsum[blockIdx.x] = sm[255];
}

__global__ void scan_bsum(int* __restrict__ bsum, int nb)
{
    __shared__ int sm[256];
    int t = threadIdx.x;
    int v = (t < nb) ? bsum[t] : 0;
    sm[t] = v; __syncthreads();
    #pragma unroll
    for (int off = 1; off < 256; off <<= 1) {
        int x = (t >= off) ? sm[t - off] : 0;
        __syncthreads();
        sm[t] += x; __syncthreads();
    }
    if (t < nb) bsum[t] = sm[t] - v;
}

__global__ void scan_add(int* __restrict__ ptr, const int* __restrict__ bsum, int n)
{
    int i = blockIdx.x * 256 + threadIdx.x;
    if (i < n) ptr[i] += bsum[blockIdx.x];
    if (i == 0) ptr[n] = ETOT;
}

__global__ void csr_fill(const int* __restrict__ src, const int* __restrict__ dst,
                         const int* __restrict__ ptr, int* __restrict__ cursor,
                         int* __restrict__ csr)
{
    int e = blockIdx.x * 256 + threadIdx.x;
    if (e >= ETOT) return;
    int s, d; edge_sd(e, s, d, src, dst);
    int pos = ptr[d] + atomicAdd(&cursor[d], 1);
    csr[pos] = s;
}

// ======================= fused GAT layer =======================
template<int H, int C, typename TIN, typename TOUT>
__global__ __launch_bounds__(256) void gat_fused(
    const TIN* __restrict__ hf, const float* __restrict__ aS,
    const float* __restrict__ aDv, const int* __restrict__ ptr,
    const int* __restrict__ csr, const float* __restrict__ bias,
    TOUT* __restrict__ out, int elu)
{
    constexpr int W = H * C;
    const int tl = threadIdx.x % W;
    const int dsub = threadIdx.x / W;
    const int d = blockIdx.x * (256 / W) + dsub;
    if (d >= NODES) return;
    const int h = tl / C, c = tl % C;
    const int beg = ptr[d], end = ptr[d + 1];
    const float aDd = aDv[d * H + h];

    // online softmax (m, den) per lane over this head's edges
    float m = -1e30f, den = 0.f;
    for (int i = beg + c; i < end; i += C) {
        int s = csr[i];
        float e = aS[s * H + h] + aDd;
        e = e > 0.f ? e : 0.2f * e;
        float M = fmaxf(m, e);
        den = den * __expf(m - M) + __expf(e - M);
        m = M;
    }
    #pragma unroll
    for (int off = C >> 1; off; off >>= 1) {
        float mo = __shfl_xor(m, off);
        float dn = __shfl_xor(den, off);
        float M = fmaxf(m, mo);
        den = den * __expf(m - M) + dn * __expf(mo - M);
        m = M;
    }

    // weighted aggregation
    float acc = 0.f;
    for (int i = beg; i < end; i++) {
        int s = csr[i];
        float e = aS[s * H + h] + aDd;
        e = e > 0.f ? e : 0.2f * e;
        float w = __expf(e - m);
        acc += w * ldf(&hf[(size_t)s * W + tl]);
    }
    float v = acc / den + bias[tl];
    if (elu) v = v > 0.f ? v : expm1f(v);
    stf(&out[(size_t)d * W + tl], v);
}

// ======================= launch =======================
extern "C" void kernel_launch(void* const* d_in, const int* in_sizes, int n_in,
                              void* d_out, int out_size, void* d_ws, size_t ws_size,
                              hipStream_t stream)
{
    const float* x   = (const float*)d_in[0];
    const int*   ei  = (const int*)d_in[1];
    const float* w1  = (const float*)d_in[2];  const float* b1  = (const float*)d_in[3];
    const float* w2  = (const float*)d_in[4];  const float* b2  = (const float*)d_in[5];
    const float* w3  = (const float*)d_in[6];  const float* b3  = (const float*)d_in[7];
    const float* wc1 = (const float*)d_in[8];  const float* as1 = (const float*)d_in[9];
    const float* ad1 = (const float*)d_in[10]; const float* bc1 = (const float*)d_in[11];
    const float* wc2 = (const float*)d_in[12]; const float* as2 = (const float*)d_in[13];
    const float* ad2 = (const float*)d_in[14]; const float* bc2 = (const float*)d_in[15];
    const float* wc3 = (const float*)d_in[16]; const float* as3 = (const float*)d_in[17];
    const float* ad3 = (const float*)d_in[18]; const float* bc3 = (const float*)d_in[19];

    const int* srcv = ei;        // [E0]
    const int* dstv = ei + E0;   // [E0]

    // -------- workspace layout (bytes) --------
    char* ws = (char*)d_ws;
    bf16*  xb    = (bf16*)(ws + 0);            // 25.6 MB  [dead after GEMM1]
    bf16*  h2b   = (bf16*)(ws + 0);            // 25.6 MB  (over xb)
    bf16*  h1b   = (bf16*)(ws + 25600000);     // 51.2 MB  [dead after GEMM2]
    bf16*  hc1b  = (bf16*)(ws + 25600000);     // 25.6 MB  (over h1b lower)
    bf16*  out1b = (bf16*)(ws + 51200000);     // 25.6 MB  (over h1b upper)
    bf16*  h3b   = (bf16*)(ws + 76800000);     // 12.8 MB  [dead after GEMM4]
    bf16*  hc2b  = (bf16*)(ws + 76800000);     // 12.8 MB  (over h3b)
    bf16*  out2b = (bf16*)(ws + 89600000);     // 12.8 MB
    float* hc3   = (float*)(ws + 102400000);   //  1.6 MB
    float* aS    = (float*)(ws + 104000000);   //  0.8 MB
    float* aD    = (float*)(ws + 104800000);   //  0.8 MB
    int*   ptr   = (int*)  (ws + 105600000);   //  50001 ints
    int*   deg   = (int*)  (ws + 105900000);   //  50000 ints (also cursor)
    int*   bsum  = (int*)  (ws + 106200000);   //  256 ints
    int*   csr   = (int*)  (ws + 106400000);   //  3.4 MB
    bf16*  w1T   = (bf16*)(ws + 110000000);    //  512x256
    bf16*  w2T   = (bf16*)(ws + 110300000);    //  256x512
    bf16*  w3T   = (bf16*)(ws + 110600000);    //  128x256
    bf16*  wc1T  = (bf16*)(ws + 110700000);    //  256x128
    bf16*  wc2T  = (bf16*)(ws + 110800000);    //  128x256
    if (ws_size < (size_t)196000000) return;

    float* outf = (float*)d_out;
    dim3 blk(256);
    const int NB_SCAN = (NODES + 255) / 256;

    // -------- CSR build --------
    (void)hipMemsetAsync(deg, 0, (size_t)NODES * 4, stream);
    deg_hist<<<(ETOT + 255)/256, blk, 0, stream>>>(srcv, dstv, deg);
    scan_block<<<NB_SCAN, blk, 0, stream>>>(deg, ptr, bsum, NODES);
    scan_bsum<<<1, blk, 0, stream>>>(bsum, NB_SCAN);
    scan_add<<<NB_SCAN, blk, 0, stream>>>(ptr, bsum, NODES);
    (void)hipMemsetAsync(deg, 0, (size_t)NODES * 4, stream);
    csr_fill<<<(ETOT + 255)/256, blk, 0, stream>>>(srcv, dstv, ptr, deg, csr);

    // -------- input/weight conversion --------
    f32_to_bf16<<<(NODES*256/4 + 255)/256, blk, 0, stream>>>(x, xb, NODES*256/4);
    w_transpose_bf16<<<(256*512 + 255)/256, blk, 0, stream>>>(w1, w1T, 256, 512);
    w_transpose_bf16<<<(512*256 + 255)/256, blk, 0, stream>>>(w2, w2T, 512, 256);
    w_transpose_bf16<<<(256*128 + 255)/256, blk, 0, stream>>>(w3, w3T, 256, 128);
    w_transpose_bf16<<<(128*256 + 255)/256, blk, 0, stream>>>(wc1, wc1T, 128, 256);
    w_transpose_bf16<<<(256*128 + 255)/256, blk, 0, stream>>>(wc2, wc2T, 256, 128);

    // -------- MLP (bf16 MFMA) --------
    const int gy = (NODES + 127) / 128;   // 391
    mfma_gemm<<<dim3(4, gy), blk, 0, stream>>>(xb,  w1T, b1, h1b, NODES, 512, 256, 1);
    mfma_gemm<<<dim3(2, gy), blk, 0, stream>>>(h1b, w2T, b2, h2b, NODES, 256, 512, 1);
    mfma_gemm<<<dim3(1, gy), blk, 0, stream>>>(h2b, w3T, b3, h3b, NODES, 128, 256, 1);

    // -------- GAT1: H=4, C=64, concat -> 256, ELU --------
    mfma_gemm<<<dim3(2, gy), blk, 0, stream>>>(h3b, wc1T, nullptr, hc1b, NODES, 256, 128, 0);
    attn_scores<bf16><<<(NODES*4*64 + 255)/256, blk, 0, stream>>>(hc1b, as1, ad1, aS, aD,
                                                                  NODES*4, 3, 64);
    gat_fused<4,64,bf16,bf16><<<NODES, blk, 0, stream>>>(hc1b, aS, aD, ptr, csr, bc1, out1b, 1);

    // -------- GAT2: H=4, C=32, concat -> 128, ELU --------
    mfma_gemm<<<dim3(1, gy), blk, 0, stream>>>(out1b, wc2T, nullptr, hc2b, NODES, 128, 256, 0);
    attn_scores<bf16><<<(NODES*4*64 + 255)/256, blk, 0, stream>>>(hc2b, as2, ad2, aS, aD,
                                                                  NODES*4, 3, 32);
    gat_fused<4,32,bf16,bf16><<<(NODES+1)/2, blk, 0, stream>>>(hc2b, aS, aD, ptr, csr, bc2, out2b, 1);

    // -------- GAT3: H=1, C=8, mean(=identity) -> 8, no ELU (fp32) --------
    gemm_n8<<<(NODES*8 + 255)/256, blk, 0, stream>>>(out2b, wc3, hc3, NODES, 128);
    attn_scores<float><<<(NODES*64 + 255)/256, blk, 0, stream>>>(hc3, as3, ad3, aS, aD,
                                                                 NODES, 0, 8);
    gat_fused<1,8,float,float><<<(NODES + 31)/32, blk, 0, stream>>>(hc3, aS, aD, ptr, csr, bc3, outf, 0);
}

// Round 5
// 677.911 us; speedup vs baseline: 2.9895x; 1.4948x over previous
//
#include <hip/hip_runtime.h>
#include <hip/hip_bf16.h>

#define NODES 50000
#define E0    800000
#define ETOT  (E0 + NODES)   // 850000 edges incl. self-loops

typedef short  short8  __attribute__((ext_vector_type(8)));
typedef unsigned short ushort8 __attribute__((ext_vector_type(8)));
typedef float  f32x4   __attribute__((ext_vector_type(4)));
typedef __hip_bfloat16 bf16;

__device__ __forceinline__ float ldf(const float* p) { return *p; }
__device__ __forceinline__ float ldf(const bf16* p)  { return __bfloat162float(*p); }
__device__ __forceinline__ void  stf(float* p, float v) { *p = v; }
__device__ __forceinline__ void  stf(bf16* p, float v)  { *p = __float2bfloat16(v); }
__device__ __forceinline__ float bfbits(unsigned short u) {
    return __uint_as_float(((unsigned)u) << 16);
}
__device__ __forceinline__ float lrelu(float x) { return x > 0.f ? x : 0.2f * x; }
__device__ __forceinline__ float pick4(float4 v, int i) {
    float r = (i == 0) ? v.x : (i == 1) ? v.y : (i == 2) ? v.z : v.w;
    return r;
}

// ======================= conversions =======================
__global__ void f32_to_bf16(const float* __restrict__ in, bf16* __restrict__ out, int n4)
{
    int i = blockIdx.x * 256 + threadIdx.x;
    if (i >= n4) return;
    float4 v = *(const float4*)(in + (size_t)i * 4);
    bf16* o = out + (size_t)i * 4;
    o[0] = __float2bfloat16(v.x); o[1] = __float2bfloat16(v.y);
    o[2] = __float2bfloat16(v.z); o[3] = __float2bfloat16(v.w);
}

// w [K][N] f32 -> wT [N][K] bf16
__global__ void w_transpose_bf16(const float* __restrict__ w, bf16* __restrict__ wt,
                                 int K, int N)
{
    int t = blockIdx.x * 256 + threadIdx.x;
    if (t >= K * N) return;
    int k = t / N, n = t % N;
    wt[(size_t)n * K + k] = __float2bfloat16(w[t]);
}

// ======================= bf16 MFMA GEMM =======================
// A [M,K] bf16 row-major, Bt [N,K] bf16 (B transposed), C [M,N] bf16.
// 128x128 tile, BK=32, 4 waves, each wave 64x64 via 4x4 mfma_f32_16x16x32_bf16.
__global__ __launch_bounds__(256) void mfma_gemm(
    const bf16* __restrict__ A, const bf16* __restrict__ Bt,
    const float* __restrict__ bias, bf16* __restrict__ C,
    int M, int N, int K, int relu)
{
    __shared__ alignas(16) unsigned short Abuf[128 * 32];
    __shared__ alignas(16) unsigned short Bbuf[128 * 32];
    const int tid  = threadIdx.x;
    const int wave = tid >> 6, lane = tid & 63;
    const int bm = blockIdx.y * 128, bn = blockIdx.x * 128;
    const int wr = (wave >> 1) * 64, wc = (wave & 1) * 64;
    const int lr = lane & 15, kg = lane >> 4;

    f32x4 acc[4][4];
    #pragma unroll
    for (int m = 0; m < 4; m++)
        #pragma unroll
        for (int n = 0; n < 4; n++)
            #pragma unroll
            for (int j = 0; j < 4; j++) acc[m][n][j] = 0.f;

    for (int k0 = 0; k0 < K; k0 += 32) {
        uint4 ra[2], rb[2];
        #pragma unroll
        for (int half = 0; half < 2; half++) {
            int t = tid + half * 256;
            int r = t >> 2, ko = (t & 3) * 8;
            int ar = bm + r; if (ar >= M) ar = M - 1;
            ra[half] = *(const uint4*)((const unsigned short*)A + (size_t)ar * K + k0 + ko);
            rb[half] = *(const uint4*)((const unsigned short*)Bt + (size_t)(bn + r) * K + k0 + ko);
        }
        __syncthreads();
        #pragma unroll
        for (int half = 0; half < 2; half++) {
            int t = tid + half * 256;
            *(uint4*)&Abuf[t * 8] = ra[half];
            *(uint4*)&Bbuf[t * 8] = rb[half];
        }
        __syncthreads();

        short8 af[4], bfr[4];
        #pragma unroll
        for (int m = 0; m < 4; m++)
            af[m] = *(const short8*)&Abuf[(wr + m * 16 + lr) * 32 + kg * 8];
        #pragma unroll
        for (int n = 0; n < 4; n++)
            bfr[n] = *(const short8*)&Bbuf[(wc + n * 16 + lr) * 32 + kg * 8];
        #pragma unroll
        for (int m = 0; m < 4; m++)
            #pragma unroll
            for (int n = 0; n < 4; n++)
                acc[m][n] = __builtin_amdgcn_mfma_f32_16x16x32_bf16(af[m], bfr[n], acc[m][n], 0, 0, 0);
    }

    // C/D layout: col = lane&15, row = (lane>>4)*4 + j
    #pragma unroll
    for (int m = 0; m < 4; m++) {
        int row0 = bm + wr + m * 16 + kg * 4;
        #pragma unroll
        for (int n = 0; n < 4; n++) {
            int col = bn + wc + n * 16 + lr;
            float bv = bias ? bias[col] : 0.f;
            #pragma unroll
            for (int j = 0; j < 4; j++) {
                int row = row0 + j;
                if (row < M) {
                    float v = acc[m][n][j] + bv;
                    if (relu) v = fmaxf(v, 0.f);
                    C[(size_t)row * N + col] = __float2bfloat16(v);
                }
            }
        }
    }
}

// Small GEMM for N=8 (wc3): one thread per (m,n). A bf16 vectorized, B f32, C f32.
__global__ void gemm_n8(const bf16* __restrict__ A, const float* __restrict__ B,
                        float* __restrict__ C, int M, int K)
{
    int t = blockIdx.x * 256 + threadIdx.x;
    int m = t >> 3, n = t & 7;
    if (m >= M) return;
    float s = 0.f;
    const ushort8* A8 = (const ushort8*)(A + (size_t)m * K);
    #pragma unroll 4
    for (int k8 = 0; k8 < K / 8; k8++) {
        ushort8 a = A8[k8];
        #pragma unroll
        for (int j = 0; j < 8; j++)
            s += bfbits(a[j]) * B[(k8 * 8 + j) * 8 + n];
    }
    C[t] = s;
}

// ======================= attention scores =======================
template<typename T>
__global__ void attn_scores(const T* __restrict__ hc, const float* __restrict__ att_s,
                            const float* __restrict__ att_d, float* __restrict__ aS,
                            float* __restrict__ aD, int nwaves, int hmask, int C)
{
    int gw = (blockIdx.x * blockDim.x + threadIdx.x) >> 6;
    int lane = threadIdx.x & 63;
    if (gw >= nwaves) return;
    int h = gw & hmask;
    float vs = 0.f, vd = 0.f;
    if (lane < C) {
        float xv = ldf(&hc[(size_t)gw * C + lane]);
        vs = xv * att_s[h * C + lane];
        vd = xv * att_d[h * C + lane];
    }
    #pragma unroll
    for (int off = 32; off; off >>= 1) {
        vs += __shfl_xor(vs, off);
        vd += __shfl_xor(vd, off);
    }
    if (lane == 0) { aS[gw] = vs; aD[gw] = vd; }
}

// ======================= CSR build (by dst) =======================
__device__ __forceinline__ void edge_sd(int e, int& s, int& d,
                                        const int* __restrict__ src,
                                        const int* __restrict__ dst) {
    if (e < E0) { s = src[e]; d = dst[e]; } else { s = e - E0; d = s; }
}

__global__ void deg_hist(const int* __restrict__ src, const int* __restrict__ dst,
                         int* __restrict__ deg)
{
    int e = blockIdx.x * 256 + threadIdx.x;
    if (e >= ETOT) return;
    int s, d; edge_sd(e, s, d, src, dst);
    atomicAdd(&deg[d], 1);
}

__global__ void scan_block(const int* __restrict__ deg, int* __restrict__ ptr,
                           int* __restrict__ bsum, int n)
{
    __shared__ int sm[256];
    int t = threadIdx.x, i = blockIdx.x * 256 + t;
    int v = (i < n) ? deg[i] : 0;
    sm[t] = v; __syncthreads();
    #pragma unroll
    for (int off = 1; off < 256; off <<= 1) {
        int x = (t >= off) ? sm[t - off] : 0;
        __syncthreads();
        sm[t] += x; __syncthreads();
    }
    if (i < n) ptr[i] = sm[t] - v;
    if (t == 255) bsum[blockIdx.x] = sm[255];
}

__global__ void scan_bsum(int* __restrict__ bsum, int nb)
{
    __shared__ int sm[256];
    int t = threadIdx.x;
    int v = (t < nb) ? bsum[t] : 0;
    sm[t] = v; __syncthreads();
    #pragma unroll
    for (int off = 1; off < 256; off <<= 1) {
        int x = (t >= off) ? sm[t - off] : 0;
        __syncthreads();
        sm[t] += x; __syncthreads();
    }
    if (t < nb) bsum[t] = sm[t] - v;
}

__global__ void scan_add(int* __restrict__ ptr, const int* __restrict__ bsum, int n)
{
    int i = blockIdx.x * 256 + threadIdx.x;
    if (i < n) ptr[i] += bsum[blockIdx.x];
    if (i == 0) ptr[n] = ETOT;
}

__global__ void csr_fill(const int* __restrict__ src, const int* __restrict__ dst,
                         const int* __restrict__ ptr, int* __restrict__ cursor,
                         int* __restrict__ csr)
{
    int e = blockIdx.x * 256 + threadIdx.x;
    if (e >= ETOT) return;
    int s, d; edge_sd(e, s, d, src, dst);
    int pos = ptr[d] + atomicAdd(&cursor[d], 1);
    csr[pos] = s;
}

// ======================= wave-per-node fused GAT (H=4) =======================
// Phase A (lane=edge): float4 score for all 4 heads, flash max/sum reduce,
// exp-weights -> LDS. Phase B (lane=8 channels): short8 gathers of h[src],
// weight from LDS; EPI lane-groups partition the edges, partial accumulators
// are butterfly-combined across groups before the single store.
template<int C>
__global__ __launch_bounds__(256) void gat_wave(
    const bf16* __restrict__ hf, const float* __restrict__ aSv,
    const float* __restrict__ aDv, const int* __restrict__ ptr,
    const int* __restrict__ csr, const float* __restrict__ bias,
    bf16* __restrict__ out, int elu)
{
    constexpr int W   = 4 * C;     // 256 / 128
    constexpr int LPE = W / 8;     // lanes per edge-row: 32 / 16
    constexpr int EPI = 64 / LPE;  // edges per iter: 2 / 4
    constexpr int CS  = (C == 64) ? 3 : 2;  // h_own = lsub >> CS

    __shared__ int    ls[4][64];
    __shared__ float4 lw[4][64];
    __shared__ int    ntl[4];

    const int wv = threadIdx.x >> 6, lane = threadIdx.x & 63;
    const int d = blockIdx.x * 4 + wv;
    const bool alive = d < NODES;
    int beg = 0, end = 0;
    if (alive) { beg = ptr[d]; end = ptr[d + 1]; }
    if (lane == 0) ntl[wv] = (end - beg + 63) >> 6;
    __syncthreads();
    const int maxt = max(max(ntl[0], ntl[1]), max(ntl[2], ntl[3]));

    const int lsub  = lane % LPE;
    const int h_own = lsub >> CS;
    const int ch0   = lsub * 8;

    float4 aDd = {0.f, 0.f, 0.f, 0.f};
    if (alive) aDd = *(const float4*)&aDv[d * 4];
    float4 m4   = {-1e30f, -1e30f, -1e30f, -1e30f};
    float4 den4 = {0.f, 0.f, 0.f, 0.f};
    float acc[8] = {};

    for (int t = 0; t < maxt; t++) {
        const int tbeg = beg + (t << 6);
        const int nval = min(64, end - tbeg);   // <=0 when this wave is done

        // ---- phase A: per-edge weights ----
        float4 e4 = {-1e30f, -1e30f, -1e30f, -1e30f};
        int s = -1;
        if (lane < nval) {
            s = csr[tbeg + lane];
            float4 a = *(const float4*)&aSv[s * 4];
            e4.x = lrelu(a.x + aDd.x); e4.y = lrelu(a.y + aDd.y);
            e4.z = lrelu(a.z + aDd.z); e4.w = lrelu(a.w + aDd.w);
        }
        float4 tm = e4;
        #pragma unroll
        for (int off = 32; off; off >>= 1) {
            tm.x = fmaxf(tm.x, __shfl_xor(tm.x, off));
            tm.y = fmaxf(tm.y, __shfl_xor(tm.y, off));
            tm.z = fmaxf(tm.z, __shfl_xor(tm.z, off));
            tm.w = fmaxf(tm.w, __shfl_xor(tm.w, off));
        }
        float4 nm = {fmaxf(m4.x, tm.x), fmaxf(m4.y, tm.y),
                     fmaxf(m4.z, tm.z), fmaxf(m4.w, tm.w)};
        float4 sc = {__expf(m4.x - nm.x), __expf(m4.y - nm.y),
                     __expf(m4.z - nm.z), __expf(m4.w - nm.w)};
        const float sco = pick4(sc, h_own);
        #pragma unroll
        for (int k = 0; k < 8; k++) acc[k] *= sco;
        den4.x *= sc.x; den4.y *= sc.y; den4.z *= sc.z; den4.w *= sc.w;
        float4 ex = {0.f, 0.f, 0.f, 0.f};
        if (s >= 0) {
            ex.x = __expf(e4.x - nm.x); ex.y = __expf(e4.y - nm.y);
            ex.z = __expf(e4.z - nm.z); ex.w = __expf(e4.w - nm.w);
        }
        float4 ts = ex;
        #pragma unroll
        for (int off = 32; off; off >>= 1) {
            ts.x += __shfl_xor(ts.x, off);
            ts.y += __shfl_xor(ts.y, off);
            ts.z += __shfl_xor(ts.z, off);
            ts.w += __shfl_xor(ts.w, off);
        }
        den4.x += ts.x; den4.y += ts.y; den4.z += ts.z; den4.w += ts.w;
        m4 = nm;
        ls[wv][lane] = s;
        lw[wv][lane] = ex;
        __syncthreads();

        // ---- phase B: weighted gather-accumulate ----
        for (int j = lane / LPE; j < nval; j += EPI) {
            const int   sj  = ls[wv][j];
            const float4 w4 = lw[wv][j];
            const float wgt = pick4(w4, h_own);
            ushort8 r = *(const ushort8*)((const unsigned short*)hf + (size_t)sj * W + ch0);
            #pragma unroll
            for (int k = 0; k < 8; k++) acc[k] += wgt * bfbits(r[k]);
        }
        __syncthreads();
    }

    // combine partial accumulators across the EPI edge-groups
    #pragma unroll
    for (int k = 0; k < 8; k++) {
        #pragma unroll
        for (int off = LPE; off < 64; off <<= 1)
            acc[k] += __shfl_xor(acc[k], off);
    }

    if (alive && lane < LPE) {
        const float deno = fmaxf(pick4(den4, h_own), 1e-16f);
        const float rden = 1.f / deno;
        ushort8 o;
        #pragma unroll
        for (int k = 0; k < 8; k++) {
            float v = acc[k] * rden + bias[ch0 + k];
            if (elu) v = v > 0.f ? v : expm1f(v);
            o[k] = (unsigned short)(__bfloat16_as_ushort(__float2bfloat16(v)));
        }
        *(ushort8*)((unsigned short*)out + (size_t)d * W + ch0) = o;
    }
}

// ======================= simple fused GAT (GAT3: H=1, C=8, fp32) =======================
template<int H, int C, typename TIN, typename TOUT>
__global__ __launch_bounds__(256) void gat_fused(
    const TIN* __restrict__ hf, const float* __restrict__ aS,
    const float* __restrict__ aDv, const int* __restrict__ ptr,
    const int* __restrict__ csr, const float* __restrict__ bias,
    TOUT* __restrict__ out, int elu)
{
    constexpr int W = H * C;
    const int tl = threadIdx.x % W;
    const int dsub = threadIdx.x / W;
    const int d = blockIdx.x * (256 / W) + dsub;
    if (d >= NODES) return;
    const int h = tl / C, c = tl % C;
    const int beg = ptr[d], end = ptr[d + 1];
    const float aDd = aDv[d * H + h];

    float m = -1e30f, den = 0.f;
    for (int i = beg + c; i < end; i += C) {
        int s = csr[i];
        float e = aS[s * H + h] + aDd;
        e = e > 0.f ? e : 0.2f * e;
        float M = fmaxf(m, e);
        den = den * __expf(m - M) + __expf(e - M);
        m = M;
    }
    #pragma unroll
    for (int off = C >> 1; off; off >>= 1) {
        float mo = __shfl_xor(m, off);
        float dn = __shfl_xor(den, off);
        float M = fmaxf(m, mo);
        den = den * __expf(m - M) + dn * __expf(mo - M);
        m = M;
    }

    float acc = 0.f;
    for (int i = beg; i < end; i++) {
        int s = csr[i];
        float e = aS[s * H + h] + aDd;
        e = e > 0.f ? e : 0.2f * e;
        float w = __expf(e - m);
        acc += w * ldf(&hf[(size_t)s * W + tl]);
    }
    float v = acc / den + bias[tl];
    if (elu) v = v > 0.f ? v : expm1f(v);
    stf(&out[(size_t)d * W + tl], v);
}

// ======================= launch =======================
extern "C" void kernel_launch(void* const* d_in, const int* in_sizes, int n_in,
                              void* d_out, int out_size, void* d_ws, size_t ws_size,
                              hipStream_t stream)
{
    const float* x   = (const float*)d_in[0];
    const int*   ei  = (const int*)d_in[1];
    const float* w1  = (const float*)d_in[2];  const float* b1  = (const float*)d_in[3];
    const float* w2  = (const float*)d_in[4];  const float* b2  = (const float*)d_in[5];
    const float* w3  = (const float*)d_in[6];  const float* b3  = (const float*)d_in[7];
    const float* wc1 = (const float*)d_in[8];  const float* as1 = (const float*)d_in[9];
    const float* ad1 = (const float*)d_in[10]; const float* bc1 = (const float*)d_in[11];
    const float* wc2 = (const float*)d_in[12]; const float* as2 = (const float*)d_in[13];
    const float* ad2 = (const float*)d_in[14]; const float* bc2 = (const float*)d_in[15];
    const float* wc3 = (const float*)d_in[16]; const float* as3 = (const float*)d_in[17];
    const float* ad3 = (const float*)d_in[18]; const float* bc3 = (const float*)d_in[19];

    const int* srcv = ei;        // [E0]
    const int* dstv = ei + E0;   // [E0]

    // -------- workspace layout (bytes) --------
    char* ws = (char*)d_ws;
    bf16*  xb    = (bf16*)(ws + 0);            // 25.6 MB  [dead after GEMM1]
    bf16*  h2b   = (bf16*)(ws + 0);            // 25.6 MB  (over xb)
    bf16*  h1b   = (bf16*)(ws + 25600000);     // 51.2 MB  [dead after GEMM2]
    bf16*  hc1b  = (bf16*)(ws + 25600000);     // 25.6 MB  (over h1b lower)
    bf16*  out1b = (bf16*)(ws + 51200000);     // 25.6 MB  (over h1b upper)
    bf16*  h3b   = (bf16*)(ws + 76800000);     // 12.8 MB  [dead after GEMM4]
    bf16*  hc2b  = (bf16*)(ws + 76800000);     // 12.8 MB  (over h3b)
    bf16*  out2b = (bf16*)(ws + 89600000);     // 12.8 MB
    float* hc3   = (float*)(ws + 102400000);   //  1.6 MB
    float* aS    = (float*)(ws + 104000000);   //  0.8 MB
    float* aD    = (float*)(ws + 104800000);   //  0.8 MB
    int*   ptr   = (int*)  (ws + 105600000);   //  50001 ints
    int*   deg   = (int*)  (ws + 105900000);   //  50000 ints (also cursor)
    int*   bsum  = (int*)  (ws + 106200000);   //  256 ints
    int*   csr   = (int*)  (ws + 106400000);   //  3.4 MB
    bf16*  w1T   = (bf16*)(ws + 110000000);
    bf16*  w2T   = (bf16*)(ws + 110300000);
    bf16*  w3T   = (bf16*)(ws + 110600000);
    bf16*  wc1T  = (bf16*)(ws + 110700000);
    bf16*  wc2T  = (bf16*)(ws + 110800000);
    if (ws_size < (size_t)196000000) return;

    float* outf = (float*)d_out;
    dim3 blk(256);
    const int NB_SCAN = (NODES + 255) / 256;

    // -------- CSR build --------
    (void)hipMemsetAsync(deg, 0, (size_t)NODES * 4, stream);
    deg_hist<<<(ETOT + 255)/256, blk, 0, stream>>>(srcv, dstv, deg);
    scan_block<<<NB_SCAN, blk, 0, stream>>>(deg, ptr, bsum, NODES);
    scan_bsum<<<1, blk, 0, stream>>>(bsum, NB_SCAN);
    scan_add<<<NB_SCAN, blk, 0, stream>>>(ptr, bsum, NODES);
    (void)hipMemsetAsync(deg, 0, (size_t)NODES * 4, stream);
    csr_fill<<<(ETOT + 255)/256, blk, 0, stream>>>(srcv, dstv, ptr, deg, csr);

    // -------- input/weight conversion --------
    f32_to_bf16<<<(NODES*256/4 + 255)/256, blk, 0, stream>>>(x, xb, NODES*256/4);
    w_transpose_bf16<<<(256*512 + 255)/256, blk, 0, stream>>>(w1, w1T, 256, 512);
    w_transpose_bf16<<<(512*256 + 255)/256, blk, 0, stream>>>(w2, w2T, 512, 256);
    w_transpose_bf16<<<(256*128 + 255)/256, blk, 0, stream>>>(w3, w3T, 256, 128);
    w_transpose_bf16<<<(128*256 + 255)/256, blk, 0, stream>>>(wc1, wc1T, 128, 256);
    w_transpose_bf16<<<(256*128 + 255)/256, blk, 0, stream>>>(wc2, wc2T, 256, 128);

    // -------- MLP (bf16 MFMA) --------
    const int gy = (NODES + 127) / 128;   // 391
    mfma_gemm<<<dim3(4, gy), blk, 0, stream>>>(xb,  w1T, b1, h1b, NODES, 512, 256, 1);
    mfma_gemm<<<dim3(2, gy), blk, 0, stream>>>(h1b, w2T, b2, h2b, NODES, 256, 512, 1);
    mfma_gemm<<<dim3(1, gy), blk, 0, stream>>>(h2b, w3T, b3, h3b, NODES, 128, 256, 1);

    // -------- GAT1: H=4, C=64, concat -> 256, ELU --------
    mfma_gemm<<<dim3(2, gy), blk, 0, stream>>>(h3b, wc1T, nullptr, hc1b, NODES, 256, 128, 0);
    attn_scores<bf16><<<(NODES*4*64 + 255)/256, blk, 0, stream>>>(hc1b, as1, ad1, aS, aD,
                                                                  NODES*4, 3, 64);
    gat_wave<64><<<(NODES + 3)/4, blk, 0, stream>>>(hc1b, aS, aD, ptr, csr, bc1, out1b, 1);

    // -------- GAT2: H=4, C=32, concat -> 128, ELU --------
    mfma_gemm<<<dim3(1, gy), blk, 0, stream>>>(out1b, wc2T, nullptr, hc2b, NODES, 128, 256, 0);
    attn_scores<bf16><<<(NODES*4*64 + 255)/256, blk, 0, stream>>>(hc2b, as2, ad2, aS, aD,
                                                                  NODES*4, 3, 32);
    gat_wave<32><<<(NODES + 3)/4, blk, 0, stream>>>(hc2b, aS, aD, ptr, csr, bc2, out2b, 1);

    // -------- GAT3: H=1, C=8, mean(=identity) -> 8, no ELU (fp32) --------
    gemm_n8<<<(NODES*8 + 255)/256, blk, 0, stream>>>(out2b, wc3, hc3, NODES, 128);
    attn_scores<float><<<(NODES*64 + 255)/256, blk, 0, stream>>>(hc3, as3, ad3, aS, aD,
                                                                 NODES, 0, 8);
    gat_fused<1,8,float,float><<<(NODES + 31)/32, blk, 0, stream>>>(hc3, aS, aD, ptr, csr, bc3, outf, 0);
}

// Round 7
// 516.844 us; speedup vs baseline: 3.9211x; 1.3116x over previous
//
#include <hip/hip_runtime.h>
#include <hip/hip_bf16.h>

#define NODES 50000
#define E0    800000
#define ETOT  (E0 + NODES)   // 850000 edges incl. self-loops

typedef short  short8  __attribute__((ext_vector_type(8)));
typedef unsigned short ushort8 __attribute__((ext_vector_type(8)));
typedef float  f32x4   __attribute__((ext_vector_type(4)));
typedef __hip_bfloat16 bf16;

__device__ __forceinline__ float ldf(const float* p) { return *p; }
__device__ __forceinline__ float ldf(const bf16* p)  { return __bfloat162float(*p); }
__device__ __forceinline__ void  stf(float* p, float v) { *p = v; }
__device__ __forceinline__ void  stf(bf16* p, float v)  { *p = __float2bfloat16(v); }
__device__ __forceinline__ float bfbits(unsigned short u) {
    return __uint_as_float(((unsigned)u) << 16);
}
__device__ __forceinline__ float lrelu(float x) { return x > 0.f ? x : 0.2f * x; }
__device__ __forceinline__ float pick4(float4 v, int i) {
    float r = (i == 0) ? v.x : (i == 1) ? v.y : (i == 2) ? v.z : v.w;
    return r;
}

// async global->LDS, 16 bytes per lane (dest = wave-uniform base + lane*16)
__device__ __forceinline__ void gload16(const void* g, unsigned short* l) {
    __builtin_amdgcn_global_load_lds(
        (const __attribute__((address_space(1))) unsigned int*)g,
        (__attribute__((address_space(3))) unsigned int*)l,
        16, 0, 0);
}

// ======================= conversions =======================
__global__ void f32_to_bf16(const float* __restrict__ in, bf16* __restrict__ out, int n4)
{
    int i = blockIdx.x * 256 + threadIdx.x;
    if (i >= n4) return;
    float4 v = *(const float4*)(in + (size_t)i * 4);
    bf16* o = out + (size_t)i * 4;
    o[0] = __float2bfloat16(v.x); o[1] = __float2bfloat16(v.y);
    o[2] = __float2bfloat16(v.z); o[3] = __float2bfloat16(v.w);
}

// w [K][N] f32 -> wT [N][K] bf16
__global__ void w_transpose_bf16(const float* __restrict__ w, bf16* __restrict__ wt,
                                 int K, int N)
{
    int t = blockIdx.x * 256 + threadIdx.x;
    if (t >= K * N) return;
    int k = t / N, n = t % N;
    wt[(size_t)n * K + k] = __float2bfloat16(w[t]);
}

// ======================= bf16 MFMA GEMM (2-phase prefetch) =======================
// A [M,K] bf16 row-major, Bt [N,K] bf16 (B transposed), C [M,N] bf16.
// 128x128 tile, BK=32, 4 waves. global_load_lds direct staging (4x16B per thread
// per K-step = full 2x8KB tile), double-buffered; stage(k+1) issued before
// compute(k); one __syncthreads per K-step (drains vmcnt).
// Epilogue staged through LDS [128][136] for coalesced stores.
__global__ __launch_bounds__(256) void mfma_gemm(
    const bf16* __restrict__ A, const bf16* __restrict__ Bt,
    const float* __restrict__ bias, bf16* __restrict__ C,
    int M, int N, int K, int relu)
{
    __shared__ union {
        unsigned short AB[2][2][128 * 32];   // [buf][A=0/B=1][row*32 + k]
        unsigned short Cs[128 * 136];        // epilogue staging (pad 136)
    } lds;

    const int tid  = threadIdx.x;
    const int wave = tid >> 6, lane = tid & 63;
    const int bm = blockIdx.y * 128, bn = blockIdx.x * 128;
    const int wr = (wave >> 1) * 64, wc = (wave & 1) * 64;
    const int lr = lane & 15, kg = lane >> 4;

    // staging: rows tid>>2 and tid>>2+64, 16B each => full 128x32 tile per matrix
    const int srow0 = tid >> 2, sko = (tid & 3) * 8;
    const int srow1 = srow0 + 64;
    int arow0 = bm + srow0; if (arow0 >= M) arow0 = M - 1;
    int arow1 = bm + srow1; if (arow1 >= M) arow1 = M - 1;
    const unsigned short* gA0 = (const unsigned short*)A + (size_t)arow0 * K + sko;
    const unsigned short* gA1 = (const unsigned short*)A + (size_t)arow1 * K + sko;
    const unsigned short* gB0 = (const unsigned short*)Bt + (size_t)(bn + srow0) * K + sko;
    const unsigned short* gB1 = (const unsigned short*)Bt + (size_t)(bn + srow1) * K + sko;

    f32x4 acc[4][4];
    #pragma unroll
    for (int m = 0; m < 4; m++)
        #pragma unroll
        for (int n = 0; n < 4; n++)
            #pragma unroll
            for (int j = 0; j < 4; j++) acc[m][n][j] = 0.f;

    const int nk = K >> 5;

    #define STAGE(buf, kk)                                              \
        gload16(gA0 + ((kk) << 5), &lds.AB[buf][0][tid * 8]);           \
        gload16(gA1 + ((kk) << 5), &lds.AB[buf][0][(tid + 256) * 8]);   \
        gload16(gB0 + ((kk) << 5), &lds.AB[buf][1][tid * 8]);           \
        gload16(gB1 + ((kk) << 5), &lds.AB[buf][1][(tid + 256) * 8]);

    // prologue: stage tile 0 into buf 0
    STAGE(0, 0)
    __syncthreads();

    int cur = 0;
    for (int k = 0; k < nk; k++) {
        if (k + 1 < nk) {   // prefetch next tile into other buffer (async)
            STAGE(cur ^ 1, k + 1)
        }
        short8 af[4], bfr[4];
        #pragma unroll
        for (int m = 0; m < 4; m++)
            af[m] = *(const short8*)&lds.AB[cur][0][(wr + m * 16 + lr) * 32 + kg * 8];
        #pragma unroll
        for (int n = 0; n < 4; n++)
            bfr[n] = *(const short8*)&lds.AB[cur][1][(wc + n * 16 + lr) * 32 + kg * 8];
        #pragma unroll
        for (int m = 0; m < 4; m++)
            #pragma unroll
            for (int n = 0; n < 4; n++)
                acc[m][n] = __builtin_amdgcn_mfma_f32_16x16x32_bf16(af[m], bfr[n], acc[m][n], 0, 0, 0);
        __syncthreads();    // drains vmcnt+lgkmcnt: prefetched tile ready, buf reusable
        cur ^= 1;
    }
    #undef STAGE

    // ---- epilogue: acc -> LDS (bf16) -> coalesced global stores ----
    // C/D layout: col = lane&15, row = (lane>>4)*4 + j
    #pragma unroll
    for (int m = 0; m < 4; m++) {
        #pragma unroll
        for (int n = 0; n < 4; n++) {
            const int col = wc + n * 16 + lr;
            const float bv = bias ? bias[bn + col] : 0.f;
            #pragma unroll
            for (int j = 0; j < 4; j++) {
                const int r = wr + m * 16 + kg * 4 + j;
                float v = acc[m][n][j] + bv;
                if (relu) v = fmaxf(v, 0.f);
                lds.Cs[r * 136 + col] = __bfloat16_as_ushort(__float2bfloat16(v));
            }
        }
    }
    __syncthreads();
    {
        const int row = tid >> 1, hf2 = tid & 1;
        const int gr = bm + row;
        if (gr < M) {
            const unsigned short* srcp = &lds.Cs[row * 136 + hf2 * 64];
            unsigned short* dstp = (unsigned short*)C + (size_t)gr * N + bn + hf2 * 64;
            #pragma unroll
            for (int i = 0; i < 8; i++)
                *(uint4*)(dstp + i * 8) = *(const uint4*)(srcp + i * 8);
        }
    }
}

// Small GEMM for N=8 (wc3): one thread per (m,n). A bf16 vectorized, B f32, C f32.
__global__ void gemm_n8(const bf16* __restrict__ A, const float* __restrict__ B,
                        float* __restrict__ C, int M, int K)
{
    int t = blockIdx.x * 256 + threadIdx.x;
    int m = t >> 3, n = t & 7;
    if (m >= M) return;
    float s = 0.f;
    const ushort8* A8 = (const ushort8*)(A + (size_t)m * K);
    #pragma unroll 4
    for (int k8 = 0; k8 < K / 8; k8++) {
        ushort8 a = A8[k8];
        #pragma unroll
        for (int j = 0; j < 8; j++)
            s += bfbits(a[j]) * B[(k8 * 8 + j) * 8 + n];
    }
    C[t] = s;
}

// ======================= attention scores =======================
template<typename T>
__global__ void attn_scores(const T* __restrict__ hc, const float* __restrict__ att_s,
                            const float* __restrict__ att_d, float* __restrict__ aS,
                            float* __restrict__ aD, int nwaves, int hmask, int C)
{
    int gw = (blockIdx.x * blockDim.x + threadIdx.x) >> 6;
    int lane = threadIdx.x & 63;
    if (gw >= nwaves) return;
    int h = gw & hmask;
    float vs = 0.f, vd = 0.f;
    if (lane < C) {
        float xv = ldf(&hc[(size_t)gw * C + lane]);
        vs = xv * att_s[h * C + lane];
        vd = xv * att_d[h * C + lane];
    }
    #pragma unroll
    for (int off = 32; off; off >>= 1) {
        vs += __shfl_xor(vs, off);
        vd += __shfl_xor(vd, off);
    }
    if (lane == 0) { aS[gw] = vs; aD[gw] = vd; }
}

// ======================= CSR build (by dst) =======================
__device__ __forceinline__ void edge_sd(int e, int& s, int& d,
                                        const int* __restrict__ src,
                                        const int* __restrict__ dst) {
    if (e < E0) { s = src[e]; d = dst[e]; } else { s = e - E0; d = s; }
}

__global__ void deg_hist(const int* __restrict__ src, const int* __restrict__ dst,
                         int* __restrict__ deg)
{
    int e = blockIdx.x * 256 + threadIdx.x;
    if (e >= ETOT) return;
    int s, d; edge_sd(e, s, d, src, dst);
    atomicAdd(&deg[d], 1);
}

__global__ void scan_block(const int* __restrict__ deg, int* __restrict__ ptr,
                           int* __restrict__ bsum, int n)
{
    __shared__ int sm[256];
    int t = threadIdx.x, i = blockIdx.x * 256 + t;
    int v = (i < n) ? deg[i] : 0;
    sm[t] = v; __syncthreads();
    #pragma unroll
    for (int off = 1; off < 256; off <<= 1) {
        int x = (t >= off) ? sm[t - off] : 0;
        __syncthreads();
        sm[t] += x; __syncthreads();
    }
    if (i < n) ptr[i] = sm[t] - v;
    if (t == 255) bsum[blockIdx.x] = sm[255];
}

__global__ void scan_bsum(int* __restrict__ bsum, int nb)
{
    __shared__ int sm[256];
    int t = threadIdx.x;
    int v = (t < nb) ? bsum[t] : 0;
    sm[t] = v; __syncthreads();
    #pragma unroll
    for (int off = 1; off < 256; off <<= 1) {
        int x = (t >= off) ? sm[t - off] : 0;
        __syncthreads();
        sm[t] += x; __syncthreads();
    }
    if (t < nb) bsum[t] = sm[t] - v;
}

__global__ void scan_add(int* __restrict__ ptr, const int* __restrict__ bsum, int n)
{
    int i = blockIdx.x * 256 + threadIdx.x;
    if (i < n) ptr[i] += bsum[blockIdx.x];
    if (i == 0) ptr[n] = ETOT;
}

__global__ void csr_fill(const int* __restrict__ src, const int* __restrict__ dst,
                         const int* __restrict__ ptr, int* __restrict__ cursor,
                         int* __restrict__ csr)
{
    int e = blockIdx.x * 256 + threadIdx.x;
    if (e >= ETOT) return;
    int s, d; edge_sd(e, s, d, src, dst);
    int pos = ptr[d] + atomicAdd(&cursor[d], 1);
    csr[pos] = s;
}

// ======================= wave-per-node fused GAT (H=4) =======================
template<int C>
__global__ __launch_bounds__(256) void gat_wave(
    const bf16* __restrict__ hf, const float* __restrict__ aSv,
    const float* __restrict__ aDv, const int* __restrict__ ptr,
    const int* __restrict__ csr, const float* __restrict__ bias,
    bf16* __restrict__ out, int elu)
{
    constexpr int W   = 4 * C;     // 256 / 128
    constexpr int LPE = W / 8;     // lanes per edge-row: 32 / 16
    constexpr int EPI = 64 / LPE;  // edges per iter: 2 / 4
    constexpr int CS  = (C == 64) ? 3 : 2;  // h_own = lsub >> CS

    __shared__ int    ls[4][64];
    __shared__ float4 lw[4][64];
    __shared__ int    ntl[4];

    const int wv = threadIdx.x >> 6, lane = threadIdx.x & 63;
    const int d = blockIdx.x * 4 + wv;
    const bool alive = d < NODES;
    int beg = 0, end = 0;
    if (alive) { beg = ptr[d]; end = ptr[d + 1]; }
    if (lane == 0) ntl[wv] = (end - beg + 63) >> 6;
    __syncthreads();
    const int maxt = max(max(ntl[0], ntl[1]), max(ntl[2], ntl[3]));

    const int lsub  = lane % LPE;
    const int h_own = lsub >> CS;
    const int ch0   = lsub * 8;

    float4 aDd = {0.f, 0.f, 0.f, 0.f};
    if (alive) aDd = *(const float4*)&aDv[d * 4];
    float4 m4   = {-1e30f, -1e30f, -1e30f, -1e30f};
    float4 den4 = {0.f, 0.f, 0.f, 0.f};
    float acc[8] = {};

    for (int t = 0; t < maxt; t++) {
        const int tbeg = beg + (t << 6);
        const int nval = min(64, end - tbeg);   // <=0 when this wave is done

        // ---- phase A: per-edge weights ----
        float4 e4 = {-1e30f, -1e30f, -1e30f, -1e30f};
        int s = -1;
        if (lane < nval) {
            s = csr[tbeg + lane];
            float4 a = *(const float4*)&aSv[s * 4];
            e4.x = lrelu(a.x + aDd.x); e4.y = lrelu(a.y + aDd.y);
            e4.z = lrelu(a.z + aDd.z); e4.w = lrelu(a.w + aDd.w);
        }
        float4 tm = e4;
        #pragma unroll
        for (int off = 32; off; off >>= 1) {
            tm.x = fmaxf(tm.x, __shfl_xor(tm.x, off));
            tm.y = fmaxf(tm.y, __shfl_xor(tm.y, off));
            tm.z = fmaxf(tm.z, __shfl_xor(tm.z, off));
            tm.w = fmaxf(tm.w, __shfl_xor(tm.w, off));
        }
        float4 nm = {fmaxf(m4.x, tm.x), fmaxf(m4.y, tm.y),
                     fmaxf(m4.z, tm.z), fmaxf(m4.w, tm.w)};
        float4 sc = {__expf(m4.x - nm.x), __expf(m4.y - nm.y),
                     __expf(m4.z - nm.z), __expf(m4.w - nm.w)};
        const float sco = pick4(sc, h_own);
        #pragma unroll
        for (int k = 0; k < 8; k++) acc[k] *= sco;
        den4.x *= sc.x; den4.y *= sc.y; den4.z *= sc.z; den4.w *= sc.w;
        float4 ex = {0.f, 0.f, 0.f, 0.f};
        if (s >= 0) {
            ex.x = __expf(e4.x - nm.x); ex.y = __expf(e4.y - nm.y);
            ex.z = __expf(e4.z - nm.z); ex.w = __expf(e4.w - nm.w);
        }
        float4 ts = ex;
        #pragma unroll
        for (int off = 32; off; off >>= 1) {
            ts.x += __shfl_xor(ts.x, off);
            ts.y += __shfl_xor(ts.y, off);
            ts.z += __shfl_xor(ts.z, off);
            ts.w += __shfl_xor(ts.w, off);
        }
        den4.x += ts.x; den4.y += ts.y; den4.z += ts.z; den4.w += ts.w;
        m4 = nm;
        ls[wv][lane] = s;
        lw[wv][lane] = ex;
        __syncthreads();

        // ---- phase B: weighted gather-accumulate ----
        for (int j = lane / LPE; j < nval; j += EPI) {
            const int   sj  = ls[wv][j];
            const float4 w4 = lw[wv][j];
            const float wgt = pick4(w4, h_own);
            ushort8 r = *(const ushort8*)((const unsigned short*)hf + (size_t)sj * W + ch0);
            #pragma unroll
            for (int k = 0; k < 8; k++) acc[k] += wgt * bfbits(r[k]);
        }
        __syncthreads();
    }

    // combine partial accumulators across the EPI edge-groups
    #pragma unroll
    for (int k = 0; k < 8; k++) {
        #pragma unroll
        for (int off = LPE; off < 64; off <<= 1)
            acc[k] += __shfl_xor(acc[k], off);
    }

    if (alive && lane < LPE) {
        const float deno = fmaxf(pick4(den4, h_own), 1e-16f);
        const float rden = 1.f / deno;
        ushort8 o;
        #pragma unroll
        for (int k = 0; k < 8; k++) {
            float v = acc[k] * rden + bias[ch0 + k];
            if (elu) v = v > 0.f ? v : expm1f(v);
            o[k] = (unsigned short)(__bfloat16_as_ushort(__float2bfloat16(v)));
        }
        *(ushort8*)((unsigned short*)out + (size_t)d * W + ch0) = o;
    }
}

// ======================= simple fused GAT (GAT3: H=1, C=8, fp32) =======================
template<int H, int C, typename TIN, typename TOUT>
__global__ __launch_bounds__(256) void gat_fused(
    const TIN* __restrict__ hf, const float* __restrict__ aS,
    const float* __restrict__ aDv, const int* __restrict__ ptr,
    const int* __restrict__ csr, const float* __restrict__ bias,
    TOUT* __restrict__ out, int elu)
{
    constexpr int W = H * C;
    const int tl = threadIdx.x % W;
    const int dsub = threadIdx.x / W;
    const int d = blockIdx.x * (256 / W) + dsub;
    if (d >= NODES) return;
    const int h = tl / C, c = tl % C;
    const int beg = ptr[d], end = ptr[d + 1];
    const float aDd = aDv[d * H + h];

    float m = -1e30f, den = 0.f;
    for (int i = beg + c; i < end; i += C) {
        int s = csr[i];
        float e = aS[s * H + h] + aDd;
        e = e > 0.f ? e : 0.2f * e;
        float M = fmaxf(m, e);
        den = den * __expf(m - M) + __expf(e - M);
        m = M;
    }
    #pragma unroll
    for (int off = C >> 1; off; off >>= 1) {
        float mo = __shfl_xor(m, off);
        float dn = __shfl_xor(den, off);
        float M = fmaxf(m, mo);
        den = den * __expf(m - M) + dn * __expf(mo - M);
        m = M;
    }

    float acc = 0.f;
    for (int i = beg; i < end; i++) {
        int s = csr[i];
        float e = aS[s * H + h] + aDd;
        e = e > 0.f ? e : 0.2f * e;
        float w = __expf(e - m);
        acc += w * ldf(&hf[(size_t)s * W + tl]);
    }
    float v = acc / den + bias[tl];
    if (elu) v = v > 0.f ? v : expm1f(v);
    stf(&out[(size_t)d * W + tl], v);
}

// ======================= launch =======================
extern "C" void kernel_launch(void* const* d_in, const int* in_sizes, int n_in,
                              void* d_out, int out_size, void* d_ws, size_t ws_size,
                              hipStream_t stream)
{
    const float* x   = (const float*)d_in[0];
    const int*   ei  = (const int*)d_in[1];
    const float* w1  = (const float*)d_in[2];  const float* b1  = (const float*)d_in[3];
    const float* w2  = (const float*)d_in[4];  const float* b2  = (const float*)d_in[5];
    const float* w3  = (const float*)d_in[6];  const float* b3  = (const float*)d_in[7];
    const float* wc1 = (const float*)d_in[8];  const float* as1 = (const float*)d_in[9];
    const float* ad1 = (const float*)d_in[10]; const float* bc1 = (const float*)d_in[11];
    const float* wc2 = (const float*)d_in[12]; const float* as2 = (const float*)d_in[13];
    const float* ad2 = (const float*)d_in[14]; const float* bc2 = (const float*)d_in[15];
    const float* wc3 = (const float*)d_in[16]; const float* as3 = (const float*)d_in[17];
    const float* ad3 = (const float*)d_in[18]; const float* bc3 = (const float*)d_in[19];

    const int* srcv = ei;        // [E0]
    const int* dstv = ei + E0;   // [E0]

    // -------- workspace layout (bytes) --------
    char* ws = (char*)d_ws;
    bf16*  xb    = (bf16*)(ws + 0);            // 25.6 MB  [dead after GEMM1]
    bf16*  h2b   = (bf16*)(ws + 0);            // 25.6 MB  (over xb)
    bf16*  h1b   = (bf16*)(ws + 25600000);     // 51.2 MB  [dead after GEMM2]
    bf16*  hc1b  = (bf16*)(ws + 25600000);     // 25.6 MB  (over h1b lower)
    bf16*  out1b = (bf16*)(ws + 51200000);     // 25.6 MB  (over h1b upper)
    bf16*  h3b   = (bf16*)(ws + 76800000);     // 12.8 MB  [dead after GEMM4]
    bf16*  hc2b  = (bf16*)(ws + 76800000);     // 12.8 MB  (over h3b)
    bf16*  out2b = (bf16*)(ws + 89600000);     // 12.8 MB
    float* hc3   = (float*)(ws + 102400000);   //  1.6 MB
    float* aS    = (float*)(ws + 104000000);   //  0.8 MB
    float* aD    = (float*)(ws + 104800000);   //  0.8 MB
    int*   ptr   = (int*)  (ws + 105600000);   //  50001 ints
    int*   deg   = (int*)  (ws + 105900000);   //  50000 ints (also cursor)
    int*   bsum  = (int*)  (ws + 106200000);   //  256 ints
    int*   csr   = (int*)  (ws + 106400000);   //  3.4 MB
    bf16*  w1T   = (bf16*)(ws + 110000000);
    bf16*  w2T   = (bf16*)(ws + 110300000);
    bf16*  w3T   = (bf16*)(ws + 110600000);
    bf16*  wc1T  = (bf16*)(ws + 110700000);
    bf16*  wc2T  = (bf16*)(ws + 110800000);
    if (ws_size < (size_t)196000000) return;

    float* outf = (float*)d_out;
    dim3 blk(256);
    const int NB_SCAN = (NODES + 255) / 256;

    // -------- CSR build --------
    (void)hipMemsetAsync(deg, 0, (size_t)NODES * 4, stream);
    deg_hist<<<(ETOT + 255)/256, blk, 0, stream>>>(srcv, dstv, deg);
    scan_block<<<NB_SCAN, blk, 0, stream>>>(deg, ptr, bsum, NODES);
    scan_bsum<<<1, blk, 0, stream>>>(bsum, NB_SCAN);
    scan_add<<<NB_SCAN, blk, 0, stream>>>(ptr, bsum, NODES);
    (void)hipMemsetAsync(deg, 0, (size_t)NODES * 4, stream);
    csr_fill<<<(ETOT + 255)/256, blk, 0, stream>>>(srcv, dstv, ptr, deg, csr);

    // -------- input/weight conversion --------
    f32_to_bf16<<<(NODES*256/4 + 255)/256, blk, 0, stream>>>(x, xb, NODES*256/4);
    w_transpose_bf16<<<(256*512 + 255)/256, blk, 0, stream>>>(w1, w1T, 256, 512);
    w_transpose_bf16<<<(512*256 + 255)/256, blk, 0, stream>>>(w2, w2T, 512, 256);
    w_transpose_bf16<<<(256*128 + 255)/256, blk, 0, stream>>>(w3, w3T, 256, 128);
    w_transpose_bf16<<<(128*256 + 255)/256, blk, 0, stream>>>(wc1, wc1T, 128, 256);
    w_transpose_bf16<<<(256*128 + 255)/256, blk, 0, stream>>>(wc2, wc2T, 256, 128);

    // -------- MLP (bf16 MFMA) --------
    const int gy = (NODES + 127) / 128;   // 391
    mfma_gemm<<<dim3(4, gy), blk, 0, stream>>>(xb,  w1T, b1, h1b, NODES, 512, 256, 1);
    mfma_gemm<<<dim3(2, gy), blk, 0, stream>>>(h1b, w2T, b2, h2b, NODES, 256, 512, 1);
    mfma_gemm<<<dim3(1, gy), blk, 0, stream>>>(h2b, w3T, b3, h3b, NODES, 128, 256, 1);

    // -------- GAT1: H=4, C=64, concat -> 256, ELU --------
    mfma_gemm<<<dim3(2, gy), blk, 0, stream>>>(h3b, wc1T, nullptr, hc1b, NODES, 256, 128, 0);
    attn_scores<bf16><<<(NODES*4*64 + 255)/256, blk, 0, stream>>>(hc1b, as1, ad1, aS, aD,
                                                                  NODES*4, 3, 64);
    gat_wave<64><<<(NODES + 3)/4, blk, 0, stream>>>(hc1b, aS, aD, ptr, csr, bc1, out1b, 1);

    // -------- GAT2: H=4, C=32, concat -> 128, ELU --------
    mfma_gemm<<<dim3(1, gy), blk, 0, stream>>>(out1b, wc2T, nullptr, hc2b, NODES, 128, 256, 0);
    attn_scores<bf16><<<(NODES*4*64 + 255)/256, blk, 0, stream>>>(hc2b, as2, ad2, aS, aD,
                                                                  NODES*4, 3, 32);
    gat_wave<32><<<(NODES + 3)/4, blk, 0, stream>>>(hc2b, aS, aD, ptr, csr, bc2, out2b, 1);

    // -------- GAT3: H=1, C=8, mean(=identity) -> 8, no ELU (fp32) --------
    gemm_n8<<<(NODES*8 + 255)/256, blk, 0, stream>>>(out2b, wc3, hc3, NODES, 128);
    attn_scores<float><<<(NODES*64 + 255)/256, blk, 0, stream>>>(hc3, as3, ad3, aS, aD,
                                                                 NODES, 0, 8);
    gat_fused<1,8,float,float><<<(NODES + 31)/32, blk, 0, stream>>>(hc3, aS, aD, ptr, csr, bc3, outf, 0);
}

// Round 8
// 435.157 us; speedup vs baseline: 4.6572x; 1.1877x over previous
//
#include <hip/hip_runtime.h>
#include <hip/hip_bf16.h>

#define NODES 50000
#define E0    800000
#define ETOT  (E0 + NODES)   // 850000 edges incl. self-loops

typedef short  short8  __attribute__((ext_vector_type(8)));
typedef unsigned short ushort8 __attribute__((ext_vector_type(8)));
typedef float  f32x4   __attribute__((ext_vector_type(4)));
typedef __hip_bfloat16 bf16;

__device__ __forceinline__ float ldf(const float* p) { return *p; }
__device__ __forceinline__ float ldf(const bf16* p)  { return __bfloat162float(*p); }
__device__ __forceinline__ void  stf(float* p, float v) { *p = v; }
__device__ __forceinline__ void  stf(bf16* p, float v)  { *p = __float2bfloat16(v); }
__device__ __forceinline__ float bfbits(unsigned short u) {
    return __uint_as_float(((unsigned)u) << 16);
}
__device__ __forceinline__ float lrelu(float x) { return x > 0.f ? x : 0.2f * x; }
__device__ __forceinline__ float pick4(float4 v, int i) {
    float r = (i == 0) ? v.x : (i == 1) ? v.y : (i == 2) ? v.z : v.w;
    return r;
}

// async global->LDS, 16 bytes per lane (dest = wave-uniform base + lane*16)
__device__ __forceinline__ void gload16(const void* g, unsigned short* l) {
    __builtin_amdgcn_global_load_lds(
        (const __attribute__((address_space(1))) unsigned int*)g,
        (__attribute__((address_space(3))) unsigned int*)l,
        16, 0, 0);
}

// ======================= conversions =======================
__global__ void f32_to_bf16(const float* __restrict__ in, bf16* __restrict__ out, int n4)
{
    int i = blockIdx.x * 256 + threadIdx.x;
    if (i >= n4) return;
    float4 v = *(const float4*)(in + (size_t)i * 4);
    bf16* o = out + (size_t)i * 4;
    o[0] = __float2bfloat16(v.x); o[1] = __float2bfloat16(v.y);
    o[2] = __float2bfloat16(v.z); o[3] = __float2bfloat16(v.w);
}

// w [K][N] f32 -> wT [N][K] bf16
__global__ void w_transpose_bf16(const float* __restrict__ w, bf16* __restrict__ wt,
                                 int K, int N)
{
    int t = blockIdx.x * 256 + threadIdx.x;
    if (t >= K * N) return;
    int k = t / N, n = t % N;
    wt[(size_t)n * K + k] = __float2bfloat16(w[t]);
}

// ======================= bf16 MFMA GEMM (2-phase prefetch) =======================
__global__ __launch_bounds__(256) void mfma_gemm(
    const bf16* __restrict__ A, const bf16* __restrict__ Bt,
    const float* __restrict__ bias, bf16* __restrict__ C,
    int M, int N, int K, int relu)
{
    __shared__ union {
        unsigned short AB[2][2][128 * 32];   // [buf][A=0/B=1][row*32 + k]
        unsigned short Cs[128 * 136];        // epilogue staging (pad 136)
    } lds;

    const int tid  = threadIdx.x;
    const int wave = tid >> 6, lane = tid & 63;
    const int bm = blockIdx.y * 128, bn = blockIdx.x * 128;
    const int wr = (wave >> 1) * 64, wc = (wave & 1) * 64;
    const int lr = lane & 15, kg = lane >> 4;

    const int srow0 = tid >> 2, sko = (tid & 3) * 8;
    const int srow1 = srow0 + 64;
    int arow0 = bm + srow0; if (arow0 >= M) arow0 = M - 1;
    int arow1 = bm + srow1; if (arow1 >= M) arow1 = M - 1;
    const unsigned short* gA0 = (const unsigned short*)A + (size_t)arow0 * K + sko;
    const unsigned short* gA1 = (const unsigned short*)A + (size_t)arow1 * K + sko;
    const unsigned short* gB0 = (const unsigned short*)Bt + (size_t)(bn + srow0) * K + sko;
    const unsigned short* gB1 = (const unsigned short*)Bt + (size_t)(bn + srow1) * K + sko;

    f32x4 acc[4][4];
    #pragma unroll
    for (int m = 0; m < 4; m++)
        #pragma unroll
        for (int n = 0; n < 4; n++)
            #pragma unroll
            for (int j = 0; j < 4; j++) acc[m][n][j] = 0.f;

    const int nk = K >> 5;

    #define STAGE(buf, kk)                                              \
        gload16(gA0 + ((kk) << 5), &lds.AB[buf][0][tid * 8]);           \
        gload16(gA1 + ((kk) << 5), &lds.AB[buf][0][(tid + 256) * 8]);   \
        gload16(gB0 + ((kk) << 5), &lds.AB[buf][1][tid * 8]);           \
        gload16(gB1 + ((kk) << 5), &lds.AB[buf][1][(tid + 256) * 8]);

    STAGE(0, 0)
    __syncthreads();

    int cur = 0;
    for (int k = 0; k < nk; k++) {
        if (k + 1 < nk) {
            STAGE(cur ^ 1, k + 1)
        }
        short8 af[4], bfr[4];
        #pragma unroll
        for (int m = 0; m < 4; m++)
            af[m] = *(const short8*)&lds.AB[cur][0][(wr + m * 16 + lr) * 32 + kg * 8];
        #pragma unroll
        for (int n = 0; n < 4; n++)
            bfr[n] = *(const short8*)&lds.AB[cur][1][(wc + n * 16 + lr) * 32 + kg * 8];
        #pragma unroll
        for (int m = 0; m < 4; m++)
            #pragma unroll
            for (int n = 0; n < 4; n++)
                acc[m][n] = __builtin_amdgcn_mfma_f32_16x16x32_bf16(af[m], bfr[n], acc[m][n], 0, 0, 0);
        __syncthreads();
        cur ^= 1;
    }
    #undef STAGE

    // epilogue: acc -> LDS (bf16) -> coalesced stores. C/D: col=lane&15, row=(lane>>4)*4+j
    #pragma unroll
    for (int m = 0; m < 4; m++) {
        #pragma unroll
        for (int n = 0; n < 4; n++) {
            const int col = wc + n * 16 + lr;
            const float bv = bias ? bias[bn + col] : 0.f;
            #pragma unroll
            for (int j = 0; j < 4; j++) {
                const int r = wr + m * 16 + kg * 4 + j;
                float v = acc[m][n][j] + bv;
                if (relu) v = fmaxf(v, 0.f);
                lds.Cs[r * 136 + col] = __bfloat16_as_ushort(__float2bfloat16(v));
            }
        }
    }
    __syncthreads();
    {
        const int row = tid >> 1, hf2 = tid & 1;
        const int gr = bm + row;
        if (gr < M) {
            const unsigned short* srcp = &lds.Cs[row * 136 + hf2 * 64];
            unsigned short* dstp = (unsigned short*)C + (size_t)gr * N + bn + hf2 * 64;
            #pragma unroll
            for (int i = 0; i < 8; i++)
                *(uint4*)(dstp + i * 8) = *(const uint4*)(srcp + i * 8);
        }
    }
}

// Small GEMM for N=8 (wc3): one thread per (m,n). A bf16 vectorized, B f32, C f32.
__global__ void gemm_n8(const bf16* __restrict__ A, const float* __restrict__ B,
                        float* __restrict__ C, int M, int K)
{
    int t = blockIdx.x * 256 + threadIdx.x;
    int m = t >> 3, n = t & 7;
    if (m >= M) return;
    float s = 0.f;
    const ushort8* A8 = (const ushort8*)(A + (size_t)m * K);
    #pragma unroll 4
    for (int k8 = 0; k8 < K / 8; k8++) {
        ushort8 a = A8[k8];
        #pragma unroll
        for (int j = 0; j < 8; j++)
            s += bfbits(a[j]) * B[(k8 * 8 + j) * 8 + n];
    }
    C[t] = s;
}

// ======================= attention scores =======================
// bf16 path: L = C/8 lanes per (node,head) pair; 16B ushort8 loads + group shuffle.
template<int C>
__global__ void attn_scores_b(const bf16* __restrict__ hc, const float* __restrict__ att_s,
                              const float* __restrict__ att_d, float* __restrict__ aS,
                              float* __restrict__ aD, int npairs)
{
    constexpr int L = C / 8;   // 8 (C=64) or 4 (C=32)
    int t = blockIdx.x * 256 + threadIdx.x;
    int gp = t / L, sub = t % L;
    if (gp >= npairs) return;
    int h = gp & 3;
    ushort8 v = *(const ushort8*)((const unsigned short*)hc + (size_t)gp * C + sub * 8);
    const float* as8 = att_s + h * C + sub * 8;
    const float* ad8 = att_d + h * C + sub * 8;
    float vs = 0.f, vd = 0.f;
    #pragma unroll
    for (int k = 0; k < 8; k++) {
        float f = bfbits(v[k]);
        vs += f * as8[k];
        vd += f * ad8[k];
    }
    #pragma unroll
    for (int off = L >> 1; off; off >>= 1) {
        vs += __shfl_xor(vs, off);
        vd += __shfl_xor(vd, off);
    }
    if (sub == 0) { aS[gp] = vs; aD[gp] = vd; }
}

// f32 path (GAT3: H=1, C=8): one wave per node, 8 active lanes.
__global__ void attn_scores_f(const float* __restrict__ hc, const float* __restrict__ att_s,
                              const float* __restrict__ att_d, float* __restrict__ aS,
                              float* __restrict__ aD, int nwaves)
{
    int gw = (blockIdx.x * blockDim.x + threadIdx.x) >> 6;
    int lane = threadIdx.x & 63;
    if (gw >= nwaves) return;
    float vs = 0.f, vd = 0.f;
    if (lane < 8) {
        float xv = hc[(size_t)gw * 8 + lane];
        vs = xv * att_s[lane];
        vd = xv * att_d[lane];
    }
    #pragma unroll
    for (int off = 4; off; off >>= 1) {
        vs += __shfl_xor(vs, off);
        vd += __shfl_xor(vd, off);
    }
    if (lane == 0) { aS[gw] = vs; aD[gw] = vd; }
}

// ======================= CSR build (by dst) =======================
__device__ __forceinline__ void edge_sd(int e, int& s, int& d,
                                        const int* __restrict__ src,
                                        const int* __restrict__ dst) {
    if (e < E0) { s = src[e]; d = dst[e]; } else { s = e - E0; d = s; }
}

__global__ void deg_hist(const int* __restrict__ src, const int* __restrict__ dst,
                         int* __restrict__ deg)
{
    int e = blockIdx.x * 256 + threadIdx.x;
    if (e >= ETOT) return;
    int s, d; edge_sd(e, s, d, src, dst);
    atomicAdd(&deg[d], 1);
}

__global__ void scan_block(const int* __restrict__ deg, int* __restrict__ ptr,
                           int* __restrict__ bsum, int n)
{
    __shared__ int sm[256];
    int t = threadIdx.x, i = blockIdx.x * 256 + t;
    int v = (i < n) ? deg[i] : 0;
    sm[t] = v; __syncthreads();
    #pragma unroll
    for (int off = 1; off < 256; off <<= 1) {
        int x = (t >= off) ? sm[t - off] : 0;
        __syncthreads();
        sm[t] += x; __syncthreads();
    }
    if (i < n) ptr[i] = sm[t] - v;
    if (t == 255) bsum[blockIdx.x] = sm[255];
}

__global__ void scan_bsum(int* __restrict__ bsum, int nb)
{
    __shared__ int sm[256];
    int t = threadIdx.x;
    int v = (t < nb) ? bsum[t] : 0;
    sm[t] = v; __syncthreads();
    #pragma unroll
    for (int off = 1; off < 256; off <<= 1) {
        int x = (t >= off) ? sm[t - off] : 0;
        __syncthreads();
        sm[t] += x; __syncthreads();
    }
    if (t < nb) bsum[t] = sm[t] - v;
}

__global__ void scan_add(int* __restrict__ ptr, const int* __restrict__ bsum, int n)
{
    int i = blockIdx.x * 256 + threadIdx.x;
    if (i < n) ptr[i] += bsum[blockIdx.x];
    if (i == 0) ptr[n] = ETOT;
}

__global__ void csr_fill(const int* __restrict__ src, const int* __restrict__ dst,
                         const int* __restrict__ ptr, int* __restrict__ cursor,
                         int* __restrict__ csr)
{
    int e = blockIdx.x * 256 + threadIdx.x;
    if (e >= ETOT) return;
    int s, d; edge_sd(e, s, d, src, dst);
    int pos = ptr[d] + atomicAdd(&cursor[d], 1);
    csr[pos] = s;
}

// ======================= wave-per-node fused GAT (H=4) =======================
// No online max (scores O(1) for this model: exp-safe); den accumulated per
// lane, reduced once. No block barriers: each wave owns its LDS slice and the
// same-wave ds_write->ds_read ordering is guaranteed (lgkmcnt). Weights stored
// transposed lwT[head][edge] (pad 68) -> 4B broadcast reads, no selects.
template<int C>
__global__ __launch_bounds__(256) void gat_wave(
    const bf16* __restrict__ hf, const float* __restrict__ aSv,
    const float* __restrict__ aDv, const int* __restrict__ ptr,
    const int* __restrict__ csr, const float* __restrict__ bias,
    bf16* __restrict__ out, int elu)
{
    constexpr int W   = 4 * C;     // 256 / 128
    constexpr int LPE = W / 8;     // lanes per edge-row: 32 / 16
    constexpr int EPI = 64 / LPE;  // edge-groups: 2 / 4
    constexpr int CS  = (C == 64) ? 3 : 2;

    __shared__ int   ls[4][64];
    __shared__ float lwT[4][4][68];   // [wave][head][edge], pad 68

    const int wv = threadIdx.x >> 6, lane = threadIdx.x & 63;
    const int d = blockIdx.x * 4 + wv;
    if (d >= NODES) return;                 // uniform per wave
    const int beg = ptr[d], end = ptr[d + 1];

    const int lsub  = lane % LPE;
    const int h_own = lsub >> CS;
    const int ch0   = lsub * 8;

    const float4 aDd = *(const float4*)&aDv[d * 4];
    float4 den4 = {0.f, 0.f, 0.f, 0.f};
    float acc[8] = {};

    for (int tbeg = beg; tbeg < end; tbeg += 64) {
        const int nval = min(64, end - tbeg);

        // ---- phase A: per-edge exp-weights (lane = edge, no reductions) ----
        if (lane < nval) {
            int s = csr[tbeg + lane];
            float4 a = *(const float4*)&aSv[s * 4];
            float4 ex;
            ex.x = __expf(lrelu(a.x + aDd.x));
            ex.y = __expf(lrelu(a.y + aDd.y));
            ex.z = __expf(lrelu(a.z + aDd.z));
            ex.w = __expf(lrelu(a.w + aDd.w));
            den4.x += ex.x; den4.y += ex.y; den4.z += ex.z; den4.w += ex.w;
            ls[wv][lane] = s;
            lwT[wv][0][lane] = ex.x;
            lwT[wv][1][lane] = ex.y;
            lwT[wv][2][lane] = ex.z;
            lwT[wv][3][lane] = ex.w;
        }
        // same-wave LDS producer->consumer: no barrier needed

        // ---- phase B: weighted gather-accumulate ----
        for (int j = lane / LPE; j < nval; j += EPI) {
            const int   sj  = ls[wv][j];
            const float wgt = lwT[wv][h_own][j];
            ushort8 r = *(const ushort8*)((const unsigned short*)hf + (size_t)sj * W + ch0);
            #pragma unroll
            for (int k = 0; k < 8; k++) acc[k] += wgt * bfbits(r[k]);
        }
    }

    // reduce den across all 64 lanes (once)
    #pragma unroll
    for (int off = 32; off; off >>= 1) {
        den4.x += __shfl_xor(den4.x, off);
        den4.y += __shfl_xor(den4.y, off);
        den4.z += __shfl_xor(den4.z, off);
        den4.w += __shfl_xor(den4.w, off);
    }
    // combine partial accumulators across the EPI edge-groups
    #pragma unroll
    for (int k = 0; k < 8; k++) {
        #pragma unroll
        for (int off = LPE; off < 64; off <<= 1)
            acc[k] += __shfl_xor(acc[k], off);
    }

    if (lane < LPE) {
        const float deno = fmaxf(pick4({den4.x, den4.y, den4.z, den4.w}, h_own), 1e-16f);
        const float rden = 1.f / deno;
        ushort8 o;
        #pragma unroll
        for (int k = 0; k < 8; k++) {
            float v = acc[k] * rden + bias[ch0 + k];
            if (elu) v = v > 0.f ? v : expm1f(v);
            o[k] = (unsigned short)(__bfloat16_as_ushort(__float2bfloat16(v)));
        }
        *(ushort8*)((unsigned short*)out + (size_t)d * W + ch0) = o;
    }
}

// ======================= simple fused GAT (GAT3: H=1, C=8, fp32) =======================
template<int H, int C, typename TIN, typename TOUT>
__global__ __launch_bounds__(256) void gat_fused(
    const TIN* __restrict__ hf, const float* __restrict__ aS,
    const float* __restrict__ aDv, const int* __restrict__ ptr,
    const int* __restrict__ csr, const float* __restrict__ bias,
    TOUT* __restrict__ out, int elu)
{
    constexpr int W = H * C;
    const int tl = threadIdx.x % W;
    const int dsub = threadIdx.x / W;
    const int d = blockIdx.x * (256 / W) + dsub;
    if (d >= NODES) return;
    const int h = tl / C, c = tl % C;
    const int beg = ptr[d], end = ptr[d + 1];
    const float aDd = aDv[d * H + h];

    float m = -1e30f, den = 0.f;
    for (int i = beg + c; i < end; i += C) {
        int s = csr[i];
        float e = aS[s * H + h] + aDd;
        e = e > 0.f ? e : 0.2f * e;
        float M = fmaxf(m, e);
        den = den * __expf(m - M) + __expf(e - M);
        m = M;
    }
    #pragma unroll
    for (int off = C >> 1; off; off >>= 1) {
        float mo = __shfl_xor(m, off);
        float dn = __shfl_xor(den, off);
        float M = fmaxf(m, mo);
        den = den * __expf(m - M) + dn * __expf(mo - M);
        m = M;
    }

    float acc = 0.f;
    for (int i = beg; i < end; i++) {
        int s = csr[i];
        float e = aS[s * H + h] + aDd;
        e = e > 0.f ? e : 0.2f * e;
        float w = __expf(e - m);
        acc += w * ldf(&hf[(size_t)s * W + tl]);
    }
    float v = acc / den + bias[tl];
    if (elu) v = v > 0.f ? v : expm1f(v);
    stf(&out[(size_t)d * W + tl], v);
}

// ======================= launch =======================
extern "C" void kernel_launch(void* const* d_in, const int* in_sizes, int n_in,
                              void* d_out, int out_size, void* d_ws, size_t ws_size,
                              hipStream_t stream)
{
    const float* x   = (const float*)d_in[0];
    const int*   ei  = (const int*)d_in[1];
    const float* w1  = (const float*)d_in[2];  const float* b1  = (const float*)d_in[3];
    const float* w2  = (const float*)d_in[4];  const float* b2  = (const float*)d_in[5];
    const float* w3  = (const float*)d_in[6];  const float* b3  = (const float*)d_in[7];
    const float* wc1 = (const float*)d_in[8];  const float* as1 = (const float*)d_in[9];
    const float* ad1 = (const float*)d_in[10]; const float* bc1 = (const float*)d_in[11];
    const float* wc2 = (const float*)d_in[12]; const float* as2 = (const float*)d_in[13];
    const float* ad2 = (const float*)d_in[14]; const float* bc2 = (const float*)d_in[15];
    const float* wc3 = (const float*)d_in[16]; const float* as3 = (const float*)d_in[17];
    const float* ad3 = (const float*)d_in[18]; const float* bc3 = (const float*)d_in[19];

    const int* srcv = ei;        // [E0]
    const int* dstv = ei + E0;   // [E0]

    // -------- workspace layout (bytes) --------
    char* ws = (char*)d_ws;
    bf16*  xb    = (bf16*)(ws + 0);            // 25.6 MB  [dead after GEMM1]
    bf16*  h2b   = (bf16*)(ws + 0);            // 25.6 MB  (over xb)
    bf16*  h1b   = (bf16*)(ws + 25600000);     // 51.2 MB  [dead after GEMM2]
    bf16*  hc1b  = (bf16*)(ws + 25600000);     // 25.6 MB  (over h1b lower)
    bf16*  out1b = (bf16*)(ws + 51200000);     // 25.6 MB  (over h1b upper)
    bf16*  h3b   = (bf16*)(ws + 76800000);     // 12.8 MB  [dead after GEMM4]
    bf16*  hc2b  = (bf16*)(ws + 76800000);     // 12.8 MB  (over h3b)
    bf16*  out2b = (bf16*)(ws + 89600000);     // 12.8 MB
    float* hc3   = (float*)(ws + 102400000);   //  1.6 MB
    float* aS    = (float*)(ws + 104000000);   //  0.8 MB
    float* aD    = (float*)(ws + 104800000);   //  0.8 MB
    int*   ptr   = (int*)  (ws + 105600000);   //  50001 ints
    int*   deg   = (int*)  (ws + 105900000);   //  50000 ints (also cursor)
    int*   bsum  = (int*)  (ws + 106200000);   //  256 ints
    int*   csr   = (int*)  (ws + 106400000);   //  3.4 MB
    bf16*  w1T   = (bf16*)(ws + 110000000);
    bf16*  w2T   = (bf16*)(ws + 110300000);
    bf16*  w3T   = (bf16*)(ws + 110600000);
    bf16*  wc1T  = (bf16*)(ws + 110700000);
    bf16*  wc2T  = (bf16*)(ws + 110800000);
    if (ws_size < (size_t)196000000) return;

    float* outf = (float*)d_out;
    dim3 blk(256);
    const int NB_SCAN = (NODES + 255) / 256;

    // -------- CSR build --------
    (void)hipMemsetAsync(deg, 0, (size_t)NODES * 4, stream);
    deg_hist<<<(ETOT + 255)/256, blk, 0, stream>>>(srcv, dstv, deg);
    scan_block<<<NB_SCAN, blk, 0, stream>>>(deg, ptr, bsum, NODES);
    scan_bsum<<<1, blk, 0, stream>>>(bsum, NB_SCAN);
    scan_add<<<NB_SCAN, blk, 0, stream>>>(ptr, bsum, NODES);
    (void)hipMemsetAsync(deg, 0, (size_t)NODES * 4, stream);
    csr_fill<<<(ETOT + 255)/256, blk, 0, stream>>>(srcv, dstv, ptr, deg, csr);

    // -------- input/weight conversion --------
    f32_to_bf16<<<(NODES*256/4 + 255)/256, blk, 0, stream>>>(x, xb, NODES*256/4);
    w_transpose_bf16<<<(256*512 + 255)/256, blk, 0, stream>>>(w1, w1T, 256, 512);
    w_transpose_bf16<<<(512*256 + 255)/256, blk, 0, stream>>>(w2, w2T, 512, 256);
    w_transpose_bf16<<<(256*128 + 255)/256, blk, 0, stream>>>(w3, w3T, 256, 128);
    w_transpose_bf16<<<(128*256 + 255)/256, blk, 0, stream>>>(wc1, wc1T, 128, 256);
    w_transpose_bf16<<<(256*128 + 255)/256, blk, 0, stream>>>(wc2, wc2T, 256, 128);

    // -------- MLP (bf16 MFMA) --------
    const int gy = (NODES + 127) / 128;   // 391
    mfma_gemm<<<dim3(4, gy), blk, 0, stream>>>(xb,  w1T, b1, h1b, NODES, 512, 256, 1);
    mfma_gemm<<<dim3(2, gy), blk, 0, stream>>>(h1b, w2T, b2, h2b, NODES, 256, 512, 1);
    mfma_gemm<<<dim3(1, gy), blk, 0, stream>>>(h2b, w3T, b3, h3b, NODES, 128, 256, 1);

    // -------- GAT1: H=4, C=64, concat -> 256, ELU --------
    mfma_gemm<<<dim3(2, gy), blk, 0, stream>>>(h3b, wc1T, nullptr, hc1b, NODES, 256, 128, 0);
    attn_scores_b<64><<<(NODES*4*8 + 255)/256, blk, 0, stream>>>(hc1b, as1, ad1, aS, aD,
                                                                 NODES*4);
    gat_wave<64><<<(NODES + 3)/4, blk, 0, stream>>>(hc1b, aS, aD, ptr, csr, bc1, out1b, 1);

    // -------- GAT2: H=4, C=32, concat -> 128, ELU --------
    mfma_gemm<<<dim3(1, gy), blk, 0, stream>>>(out1b, wc2T, nullptr, hc2b, NODES, 128, 256, 0);
    attn_scores_b<32><<<(NODES*4*4 + 255)/256, blk, 0, stream>>>(hc2b, as2, ad2, aS, aD,
                                                                 NODES*4);
    gat_wave<32><<<(NODES + 3)/4, blk, 0, stream>>>(hc2b, aS, aD, ptr, csr, bc2, out2b, 1);

    // -------- GAT3: H=1, C=8, mean(=identity) -> 8, no ELU (fp32) --------
    gemm_n8<<<(NODES*8 + 255)/256, blk, 0, stream>>>(out2b, wc3, hc3, NODES, 128);
    attn_scores_f<<<(NODES*64 + 255)/256, blk, 0, stream>>>(hc3, as3, ad3, aS, aD, NODES);
    gat_fused<1,8,float,float><<<(NODES + 31)/32, blk, 0, stream>>>(hc3, aS, aD, ptr, csr, bc3, outf, 0);
}

// Round 9
// 420.526 us; speedup vs baseline: 4.8192x; 1.0348x over previous
//
#include <hip/hip_runtime.h>
#include <hip/hip_bf16.h>

#define NODES 50000
#define E0    800000
#define ETOT  (E0 + NODES)   // 850000 edges incl. self-loops

typedef short  short8  __attribute__((ext_vector_type(8)));
typedef unsigned short ushort8 __attribute__((ext_vector_type(8)));
typedef float  f32x4   __attribute__((ext_vector_type(4)));
typedef __hip_bfloat16 bf16;

__device__ __forceinline__ float bfbits(unsigned short u) {
    return __uint_as_float(((unsigned)u) << 16);
}
__device__ __forceinline__ float lrelu(float x) { return x > 0.f ? x : 0.2f * x; }
__device__ __forceinline__ float pick4(float4 v, int i) {
    float r = (i == 0) ? v.x : (i == 1) ? v.y : (i == 2) ? v.z : v.w;
    return r;
}

// async global->LDS, 16 bytes per lane (dest = wave-uniform base + lane*16)
__device__ __forceinline__ void gload16(const void* g, unsigned short* l) {
    __builtin_amdgcn_global_load_lds(
        (const __attribute__((address_space(1))) unsigned int*)g,
        (__attribute__((address_space(3))) unsigned int*)l,
        16, 0, 0);
}

// ======================= conversions =======================
__global__ void f32_to_bf16(const float* __restrict__ in, bf16* __restrict__ out, int n4)
{
    int i = blockIdx.x * 256 + threadIdx.x;
    if (i >= n4) return;
    float4 v = *(const float4*)(in + (size_t)i * 4);
    bf16* o = out + (size_t)i * 4;
    o[0] = __float2bfloat16(v.x); o[1] = __float2bfloat16(v.y);
    o[2] = __float2bfloat16(v.z); o[3] = __float2bfloat16(v.w);
}

__device__ __forceinline__ void wtr(const float* w, bf16* wt, int K, int N, int t)
{
    int k = t / N, n = t % N;
    wt[(size_t)n * K + k] = __float2bfloat16(w[t]);
}

// all five weight transposes in one launch
__global__ void w_transpose_all(
    const float* w1, const float* w2, const float* w3,
    const float* wc1, const float* wc2,
    bf16* w1T, bf16* w2T, bf16* w3T, bf16* wc1T, bf16* wc2T)
{
    int t = blockIdx.x * 256 + threadIdx.x;
    if      (t < 131072)  wtr(w1,  w1T,  256, 512, t);
    else if (t < 262144)  wtr(w2,  w2T,  512, 256, t - 131072);
    else if (t < 294912)  wtr(w3,  w3T,  256, 128, t - 262144);
    else if (t < 327680)  wtr(wc1, wc1T, 128, 256, t - 294912);
    else if (t < 360448)  wtr(wc2, wc2T, 256, 128, t - 327680);
}

// ======================= bf16 MFMA GEMM (2-phase prefetch) =======================
// SLC = 0: plain GEMM. SLC = 64/32: also emit GAT attention scores
// aSo/aDo[row*4+head] from the epilogue registers (head width = SLC channels).
template<int SLC>
__global__ __launch_bounds__(256) void mfma_gemm(
    const bf16* __restrict__ A, const bf16* __restrict__ Bt,
    const float* __restrict__ bias, bf16* __restrict__ C,
    int M, int N, int K, int relu,
    const float* __restrict__ att_s, const float* __restrict__ att_d,
    float* __restrict__ aSo, float* __restrict__ aDo)
{
    __shared__ union {
        unsigned short AB[2][2][128 * 32];   // [buf][A=0/B=1][row*32 + k]
        unsigned short Cs[128 * 136];        // epilogue staging (pad 136)
    } lds;

    const int tid  = threadIdx.x;
    const int wave = tid >> 6, lane = tid & 63;
    const int bm = blockIdx.y * 128, bn = blockIdx.x * 128;
    const int wr = (wave >> 1) * 64, wc = (wave & 1) * 64;
    const int lr = lane & 15, kg = lane >> 4;

    const int srow0 = tid >> 2, sko = (tid & 3) * 8;
    const int srow1 = srow0 + 64;
    int arow0 = bm + srow0; if (arow0 >= M) arow0 = M - 1;
    int arow1 = bm + srow1; if (arow1 >= M) arow1 = M - 1;
    const unsigned short* gA0 = (const unsigned short*)A + (size_t)arow0 * K + sko;
    const unsigned short* gA1 = (const unsigned short*)A + (size_t)arow1 * K + sko;
    const unsigned short* gB0 = (const unsigned short*)Bt + (size_t)(bn + srow0) * K + sko;
    const unsigned short* gB1 = (const unsigned short*)Bt + (size_t)(bn + srow1) * K + sko;

    f32x4 acc[4][4];
    #pragma unroll
    for (int m = 0; m < 4; m++)
        #pragma unroll
        for (int n = 0; n < 4; n++)
            #pragma unroll
            for (int j = 0; j < 4; j++) acc[m][n][j] = 0.f;

    const int nk = K >> 5;

    #define STAGE(buf, kk)                                              \
        gload16(gA0 + ((kk) << 5), &lds.AB[buf][0][tid * 8]);           \
        gload16(gA1 + ((kk) << 5), &lds.AB[buf][0][(tid + 256) * 8]);   \
        gload16(gB0 + ((kk) << 5), &lds.AB[buf][1][tid * 8]);           \
        gload16(gB1 + ((kk) << 5), &lds.AB[buf][1][(tid + 256) * 8]);

    STAGE(0, 0)
    __syncthreads();

    int cur = 0;
    for (int k = 0; k < nk; k++) {
        if (k + 1 < nk) {
            STAGE(cur ^ 1, k + 1)
        }
        short8 af[4], bfr[4];
        #pragma unroll
        for (int m = 0; m < 4; m++)
            af[m] = *(const short8*)&lds.AB[cur][0][(wr + m * 16 + lr) * 32 + kg * 8];
        #pragma unroll
        for (int n = 0; n < 4; n++)
            bfr[n] = *(const short8*)&lds.AB[cur][1][(wc + n * 16 + lr) * 32 + kg * 8];
        #pragma unroll
        for (int m = 0; m < 4; m++)
            #pragma unroll
            for (int n = 0; n < 4; n++)
                acc[m][n] = __builtin_amdgcn_mfma_f32_16x16x32_bf16(af[m], bfr[n], acc[m][n], 0, 0, 0);
        __syncthreads();
        cur ^= 1;
    }
    #undef STAGE

    // epilogue: acc -> LDS (bf16) -> coalesced stores. C/D: col=lane&15, row=(lane>>4)*4+j
    #pragma unroll
    for (int m = 0; m < 4; m++) {
        #pragma unroll
        for (int n = 0; n < 4; n++) {
            const int col = wc + n * 16 + lr;
            const float bv = bias ? bias[bn + col] : 0.f;
            #pragma unroll
            for (int j = 0; j < 4; j++) {
                const int r = wr + m * 16 + kg * 4 + j;
                float v = acc[m][n][j] + bv;
                if (relu) v = fmaxf(v, 0.f);
                lds.Cs[r * 136 + col] = __bfloat16_as_ushort(__float2bfloat16(v));
            }
        }
    }
    __syncthreads();
    {
        const int row = tid >> 1, hf2 = tid & 1;
        const int gr = bm + row;
        if (gr < M) {
            const unsigned short* srcp = &lds.Cs[row * 136 + hf2 * 64];
            unsigned short* dstp = (unsigned short*)C + (size_t)gr * N + bn + hf2 * 64;
            ushort8 chunk[8];
            #pragma unroll
            for (int i = 0; i < 8; i++) chunk[i] = *(const ushort8*)(srcp + i * 8);
            #pragma unroll
            for (int i = 0; i < 8; i++) *(ushort8*)(dstp + i * 8) = chunk[i];
            if constexpr (SLC > 0) {
                constexpr int NH = 64 / SLC;          // heads in this 64-col segment
                const int seg0 = bn + hf2 * 64;
                #pragma unroll
                for (int hh = 0; hh < NH; hh++) {
                    const int head = (seg0 >> (SLC == 64 ? 6 : 5)) + hh;
                    const float* asv = att_s + head * SLC;
                    const float* adv = att_d + head * SLC;
                    float vs = 0.f, vd = 0.f;
                    #pragma unroll
                    for (int i = 0; i < SLC; i++) {
                        const int idx = hh * SLC + i;
                        float f = bfbits(chunk[idx >> 3][idx & 7]);
                        vs = fmaf(f, asv[i], vs);
                        vd = fmaf(f, adv[i], vd);
                    }
                    aSo[gr * 4 + head] = vs;
                    aDo[gr * 4 + head] = vd;
                }
            }
        }
    }
}

// Small GEMM for N=8 (wc3) + fused GAT3 scores: one thread per (m,n).
__global__ void gemm_n8_scores(const bf16* __restrict__ A, const float* __restrict__ B,
                               float* __restrict__ C, int M, int K,
                               const float* __restrict__ as3, const float* __restrict__ ad3,
                               float* __restrict__ aS, float* __restrict__ aD)
{
    int t = blockIdx.x * 256 + threadIdx.x;
    int m = t >> 3, n = t & 7;
    if (m >= M) return;
    float s = 0.f;
    const ushort8* A8 = (const ushort8*)((const unsigned short*)A + (size_t)m * K);
    #pragma unroll 4
    for (int k8 = 0; k8 < K / 8; k8++) {
        ushort8 a = A8[k8];
        #pragma unroll
        for (int j = 0; j < 8; j++)
            s += bfbits(a[j]) * B[(k8 * 8 + j) * 8 + n];
    }
    C[t] = s;
    // fused scores: aS[m] = sum_n s*as3[n] (8-lane aligned shuffle reduce)
    float vs = s * as3[n], vd = s * ad3[n];
    #pragma unroll
    for (int off = 1; off < 8; off <<= 1) {
        vs += __shfl_xor(vs, off);
        vd += __shfl_xor(vd, off);
    }
    if (n == 0) { aS[m] = vs; aD[m] = vd; }
}

// ======================= CSR build (by dst) =======================
__device__ __forceinline__ void edge_sd(int e, int& s, int& d,
                                        const int* __restrict__ src,
                                        const int* __restrict__ dst) {
    if (e < E0) { s = src[e]; d = dst[e]; } else { s = e - E0; d = s; }
}

__global__ void deg_hist(const int* __restrict__ src, const int* __restrict__ dst,
                         int* __restrict__ deg)
{
    int e = blockIdx.x * 256 + threadIdx.x;
    if (e >= ETOT) return;
    int s, d; edge_sd(e, s, d, src, dst);
    atomicAdd(&deg[d], 1);
}

__global__ void scan_block(const int* __restrict__ deg, int* __restrict__ ptr,
                           int* __restrict__ bsum, int n)
{
    __shared__ int sm[256];
    int t = threadIdx.x, i = blockIdx.x * 256 + t;
    int v = (i < n) ? deg[i] : 0;
    sm[t] = v; __syncthreads();
    #pragma unroll
    for (int off = 1; off < 256; off <<= 1) {
        int x = (t >= off) ? sm[t - off] : 0;
        __syncthreads();
        sm[t] += x; __syncthreads();
    }
    if (i < n) ptr[i] = sm[t] - v;
    if (t == 255) bsum[blockIdx.x] = sm[255];
}

__global__ void scan_bsum(int* __restrict__ bsum, int nb)
{
    __shared__ int sm[256];
    int t = threadIdx.x;
    int v = (t < nb) ? bsum[t] : 0;
    sm[t] = v; __syncthreads();
    #pragma unroll
    for (int off = 1; off < 256; off <<= 1) {
        int x = (t >= off) ? sm[t - off] : 0;
        __syncthreads();
        sm[t] += x; __syncthreads();
    }
    if (t < nb) bsum[t] = sm[t] - v;
}

__global__ void scan_add(int* __restrict__ ptr, const int* __restrict__ bsum, int n)
{
    int i = blockIdx.x * 256 + threadIdx.x;
    if (i < n) ptr[i] += bsum[blockIdx.x];
    if (i == 0) ptr[n] = ETOT;
}

__global__ void csr_fill(const int* __restrict__ src, const int* __restrict__ dst,
                         const int* __restrict__ ptr, int* __restrict__ cursor,
                         int* __restrict__ csr)
{
    int e = blockIdx.x * 256 + threadIdx.x;
    if (e >= ETOT) return;
    int s, d; edge_sd(e, s, d, src, dst);
    int pos = ptr[d] + atomicAdd(&cursor[d], 1);
    csr[pos] = s;
}

// ======================= wave-per-node fused GAT (H=4) =======================
template<int C>
__global__ __launch_bounds__(256) void gat_wave(
    const bf16* __restrict__ hf, const float* __restrict__ aSv,
    const float* __restrict__ aDv, const int* __restrict__ ptr,
    const int* __restrict__ csr, const float* __restrict__ bias,
    bf16* __restrict__ out, int elu)
{
    constexpr int W   = 4 * C;     // 256 / 128
    constexpr int LPE = W / 8;     // lanes per edge-row: 32 / 16
    constexpr int EPI = 64 / LPE;  // edge-groups: 2 / 4
    constexpr int CS  = (C == 64) ? 3 : 2;

    __shared__ int   ls[4][64];
    __shared__ float lwT[4][4][68];   // [wave][head][edge], pad 68

    const int wv = threadIdx.x >> 6, lane = threadIdx.x & 63;
    const int d = blockIdx.x * 4 + wv;
    if (d >= NODES) return;                 // uniform per wave
    const int beg = ptr[d], end = ptr[d + 1];

    const int lsub  = lane % LPE;
    const int h_own = lsub >> CS;
    const int ch0   = lsub * 8;

    const float4 aDd = *(const float4*)&aDv[d * 4];
    float4 den4 = {0.f, 0.f, 0.f, 0.f};
    float acc[8] = {};

    for (int tbeg = beg; tbeg < end; tbeg += 64) {
        const int nval = min(64, end - tbeg);

        // ---- phase A: per-edge exp-weights (lane = edge, no reductions) ----
        if (lane < nval) {
            int s = csr[tbeg + lane];
            float4 a = *(const float4*)&aSv[s * 4];
            float4 ex;
            ex.x = __expf(lrelu(a.x + aDd.x));
            ex.y = __expf(lrelu(a.y + aDd.y));
            ex.z = __expf(lrelu(a.z + aDd.z));
            ex.w = __expf(lrelu(a.w + aDd.w));
            den4.x += ex.x; den4.y += ex.y; den4.z += ex.z; den4.w += ex.w;
            ls[wv][lane] = s;
            lwT[wv][0][lane] = ex.x;
            lwT[wv][1][lane] = ex.y;
            lwT[wv][2][lane] = ex.z;
            lwT[wv][3][lane] = ex.w;
        }
        // same-wave LDS producer->consumer: no barrier needed

        // ---- phase B: weighted gather-accumulate ----
        for (int j = lane / LPE; j < nval; j += EPI) {
            const int   sj  = ls[wv][j];
            const float wgt = lwT[wv][h_own][j];
            ushort8 r = *(const ushort8*)((const unsigned short*)hf + (size_t)sj * W + ch0);
            #pragma unroll
            for (int k = 0; k < 8; k++) acc[k] += wgt * bfbits(r[k]);
        }
    }

    // reduce den across all 64 lanes (once)
    #pragma unroll
    for (int off = 32; off; off >>= 1) {
        den4.x += __shfl_xor(den4.x, off);
        den4.y += __shfl_xor(den4.y, off);
        den4.z += __shfl_xor(den4.z, off);
        den4.w += __shfl_xor(den4.w, off);
    }
    // combine partial accumulators across the EPI edge-groups
    #pragma unroll
    for (int k = 0; k < 8; k++) {
        #pragma unroll
        for (int off = LPE; off < 64; off <<= 1)
            acc[k] += __shfl_xor(acc[k], off);
    }

    if (lane < LPE) {
        const float deno = fmaxf(pick4({den4.x, den4.y, den4.z, den4.w}, h_own), 1e-16f);
        const float rden = 1.f / deno;
        ushort8 o;
        #pragma unroll
        for (int k = 0; k < 8; k++) {
            float v = acc[k] * rden + bias[ch0 + k];
            if (elu) v = v > 0.f ? v : expm1f(v);
            o[k] = (unsigned short)(__bfloat16_as_ushort(__float2bfloat16(v)));
        }
        *(ushort8*)((unsigned short*)out + (size_t)d * W + ch0) = o;
    }
}

// ======================= GAT3: one-pass (H=1, C=8, fp32, no ELU) =======================
__global__ void gat3_onepass(const float* __restrict__ hc3, const float* __restrict__ aS,
                             const float* __restrict__ aD, const int* __restrict__ ptr,
                             const int* __restrict__ csr, const float* __restrict__ bias,
                             float* __restrict__ out)
{
    int t = blockIdx.x * 256 + threadIdx.x;
    int d = t >> 3, c = t & 7;
    if (d >= NODES) return;
    const int beg = ptr[d], end = ptr[d + 1];
    const float aDd = aD[d];
    float acc = 0.f, den = 0.f;
    for (int i = beg; i < end; i++) {
        int s = csr[i];
        float ex = __expf(lrelu(aS[s] + aDd));
        den += ex;
        acc += ex * hc3[s * 8 + c];
    }
    out[d * 8 + c] = acc / fmaxf(den, 1e-16f) + bias[c];
}

// ======================= launch =======================
extern "C" void kernel_launch(void* const* d_in, const int* in_sizes, int n_in,
                              void* d_out, int out_size, void* d_ws, size_t ws_size,
                              hipStream_t stream)
{
    const float* x   = (const float*)d_in[0];
    const int*   ei  = (const int*)d_in[1];
    const float* w1  = (const float*)d_in[2];  const float* b1  = (const float*)d_in[3];
    const float* w2  = (const float*)d_in[4];  const float* b2  = (const float*)d_in[5];
    const float* w3  = (const float*)d_in[6];  const float* b3  = (const float*)d_in[7];
    const float* wc1 = (const float*)d_in[8];  const float* as1 = (const float*)d_in[9];
    const float* ad1 = (const float*)d_in[10]; const float* bc1 = (const float*)d_in[11];
    const float* wc2 = (const float*)d_in[12]; const float* as2 = (const float*)d_in[13];
    const float* ad2 = (const float*)d_in[14]; const float* bc2 = (const float*)d_in[15];
    const float* wc3 = (const float*)d_in[16]; const float* as3 = (const float*)d_in[17];
    const float* ad3 = (const float*)d_in[18]; const float* bc3 = (const float*)d_in[19];

    const int* srcv = ei;        // [E0]
    const int* dstv = ei + E0;   // [E0]

    // -------- workspace layout (bytes) --------
    char* ws = (char*)d_ws;
    bf16*  xb    = (bf16*)(ws + 0);            // 25.6 MB  [dead after GEMM1]
    bf16*  h2b   = (bf16*)(ws + 0);            // 25.6 MB  (over xb)
    bf16*  h1b   = (bf16*)(ws + 25600000);     // 51.2 MB  [dead after GEMM2]
    bf16*  hc1b  = (bf16*)(ws + 25600000);     // 25.6 MB  (over h1b lower)
    bf16*  out1b = (bf16*)(ws + 51200000);     // 25.6 MB  (over h1b upper)
    bf16*  h3b   = (bf16*)(ws + 76800000);     // 12.8 MB  [dead after GEMM4]
    bf16*  hc2b  = (bf16*)(ws + 76800000);     // 12.8 MB  (over h3b)
    bf16*  out2b = (bf16*)(ws + 89600000);     // 12.8 MB
    float* hc3   = (float*)(ws + 102400000);   //  1.6 MB
    float* aS    = (float*)(ws + 104000000);   //  0.8 MB
    float* aD    = (float*)(ws + 104800000);   //  0.8 MB
    int*   ptr   = (int*)  (ws + 105600000);   //  50001 ints
    int*   deg   = (int*)  (ws + 105900000);   //  200000 B
    int*   curs  = (int*)  (ws + 106100000);   //  200000 B (zeroed with deg, 1 memset)
    int*   bsum  = (int*)  (ws + 106300000);   //  256 ints
    int*   csr   = (int*)  (ws + 106400000);   //  3.4 MB
    bf16*  w1T   = (bf16*)(ws + 110000000);
    bf16*  w2T   = (bf16*)(ws + 110300000);
    bf16*  w3T   = (bf16*)(ws + 110600000);
    bf16*  wc1T  = (bf16*)(ws + 110700000);
    bf16*  wc2T  = (bf16*)(ws + 110800000);
    if (ws_size < (size_t)196000000) return;

    float* outf = (float*)d_out;
    dim3 blk(256);
    const int NB_SCAN = (NODES + 255) / 256;

    // -------- CSR build --------
    (void)hipMemsetAsync(deg, 0, (size_t)400000, stream);   // deg + cursor
    deg_hist<<<(ETOT + 255)/256, blk, 0, stream>>>(srcv, dstv, deg);
    scan_block<<<NB_SCAN, blk, 0, stream>>>(deg, ptr, bsum, NODES);
    scan_bsum<<<1, blk, 0, stream>>>(bsum, NB_SCAN);
    scan_add<<<NB_SCAN, blk, 0, stream>>>(ptr, bsum, NODES);
    csr_fill<<<(ETOT + 255)/256, blk, 0, stream>>>(srcv, dstv, ptr, curs, csr);

    // -------- input/weight conversion --------
    f32_to_bf16<<<(NODES*256/4 + 255)/256, blk, 0, stream>>>(x, xb, NODES*256/4);
    w_transpose_all<<<(360448 + 255)/256, blk, 0, stream>>>(w1, w2, w3, wc1, wc2,
                                                            w1T, w2T, w3T, wc1T, wc2T);

    // -------- MLP (bf16 MFMA) --------
    const int gy = (NODES + 127) / 128;   // 391
    mfma_gemm<0><<<dim3(4, gy), blk, 0, stream>>>(xb,  w1T, b1, h1b, NODES, 512, 256, 1,
                                                  nullptr, nullptr, nullptr, nullptr);
    mfma_gemm<0><<<dim3(2, gy), blk, 0, stream>>>(h1b, w2T, b2, h2b, NODES, 256, 512, 1,
                                                  nullptr, nullptr, nullptr, nullptr);
    mfma_gemm<0><<<dim3(1, gy), blk, 0, stream>>>(h2b, w3T, b3, h3b, NODES, 128, 256, 1,
                                                  nullptr, nullptr, nullptr, nullptr);

    // -------- GAT1: H=4, C=64, concat -> 256, ELU (scores fused in GEMM) --------
    mfma_gemm<64><<<dim3(2, gy), blk, 0, stream>>>(h3b, wc1T, nullptr, hc1b, NODES, 256, 128, 0,
                                                   as1, ad1, aS, aD);
    gat_wave<64><<<(NODES + 3)/4, blk, 0, stream>>>(hc1b, aS, aD, ptr, csr, bc1, out1b, 1);

    // -------- GAT2: H=4, C=32, concat -> 128, ELU (scores fused in GEMM) --------
    mfma_gemm<32><<<dim3(1, gy), blk, 0, stream>>>(out1b, wc2T, nullptr, hc2b, NODES, 128, 256, 0,
                                                   as2, ad2, aS, aD);
    gat_wave<32><<<(NODES + 3)/4, blk, 0, stream>>>(hc2b, aS, aD, ptr, csr, bc2, out2b, 1);

    // -------- GAT3: H=1, C=8, mean(=identity) -> 8, no ELU (fp32) --------
    gemm_n8_scores<<<(NODES*8 + 255)/256, blk, 0, stream>>>(out2b, wc3, hc3, NODES, 128,
                                                            as3, ad3, aS, aD);
    gat3_onepass<<<(NODES*8 + 255)/256, blk, 0, stream>>>(hc3, aS, aD, ptr, csr, bc3, outf);
}